// Round 4
// baseline (117110.291 us; speedup 1.0000x reference)
//
#include <hip/hip_runtime.h>
#include <hip/hip_fp16.h>
#include <stdint.h>

#define Bsz 128
#define Ssz 512
#define Vsz 600
#define Hsz 512
#define Tsz 121
#define NBLK 512

// branch-free 6-op tanh: tanh(x) = 1 - 2/(1 + e^{2x}); exact at +/-inf, ~1e-6 abs err
__device__ __forceinline__ float fast_tanh(float x) {
  float e = __expf(x + x);
  return 1.0f - __fdividef(2.0f, 1.0f + e);
}

// ---------------- H_proj(fp16) = batch_H @ W_i2h^T ----------------
__global__ __launch_bounds__(256) void k_hp(const float* __restrict__ bH,
                                            const float* __restrict__ Wi,
                                            __half* __restrict__ Hp) {
  __shared__ float As[16][604];
  int m0 = blockIdx.x * 16;
  for (int idx = threadIdx.x; idx < 16 * 600; idx += 256) {
    int r = idx / 600, k = idx - r * 600;
    As[r][k] = bH[(size_t)(m0 + r) * 600 + k];
  }
  __syncthreads();
  int rg = threadIdx.x & 3, cg = threadIdx.x >> 2;
  int r0 = rg * 4;
  for (int pass = 0; pass < 2; ++pass) {
    int c0 = pass * 256 + cg * 4;
    float acc[4][4] = {};
    const float* w0p = Wi + (size_t)(c0 + 0) * 600;
    const float* w1p = Wi + (size_t)(c0 + 1) * 600;
    const float* w2p = Wi + (size_t)(c0 + 2) * 600;
    const float* w3p = Wi + (size_t)(c0 + 3) * 600;
    for (int k = 0; k < 600; k += 4) {
      float4 w0 = *(const float4*)(w0p + k);
      float4 w1 = *(const float4*)(w1p + k);
      float4 w2 = *(const float4*)(w2p + k);
      float4 w3 = *(const float4*)(w3p + k);
#pragma unroll
      for (int i = 0; i < 4; ++i) {
        float4 a = *(const float4*)&As[r0 + i][k];
        acc[i][0] += a.x * w0.x + a.y * w0.y + a.z * w0.z + a.w * w0.w;
        acc[i][1] += a.x * w1.x + a.y * w1.y + a.z * w1.z + a.w * w1.w;
        acc[i][2] += a.x * w2.x + a.y * w2.y + a.z * w2.z + a.w * w2.w;
        acc[i][3] += a.x * w3.x + a.y * w3.y + a.z * w3.z + a.w * w3.w;
      }
    }
#pragma unroll
    for (int i = 0; i < 4; ++i) {
      __half2 p01 = __floats2half2_rn(acc[i][0], acc[i][1]);
      __half2 p23 = __floats2half2_rn(acc[i][2], acc[i][3]);
      union { __half2 h2[2]; float2 f2; } u;
      u.h2[0] = p01; u.h2[1] = p23;
      *(float2*)&Hp[(size_t)(m0 + r0 + i) * Hsz + c0] = u.f2;
    }
  }
}

// ---------------- persistent step loop ----------------
struct ShPP { float hs[512]; float part[128]; };
struct ShE  { float pps[512]; float wss[512]; float part[128]; };
struct ShC  { float al[512]; float wred[8]; float part[3][3][64]; };
struct ShG  { float xs[4][1112]; float4 part[4][32]; };
union ShU { ShPP pp; ShE e; ShC c; ShG g; };

__device__ __forceinline__ void gridbar(unsigned* bar) {
  __syncthreads();
  if (threadIdx.x == 0) {
    __threadfence();
    unsigned g = __hip_atomic_load(&bar[1], __ATOMIC_RELAXED, __HIP_MEMORY_SCOPE_AGENT);
    unsigned a = __hip_atomic_fetch_add(&bar[0], 1u, __ATOMIC_ACQ_REL, __HIP_MEMORY_SCOPE_AGENT);
    if (a == (unsigned)(NBLK - 1)) {
      __hip_atomic_store(&bar[0], 0u, __ATOMIC_RELAXED, __HIP_MEMORY_SCOPE_AGENT);
      __hip_atomic_fetch_add(&bar[1], 1u, __ATOMIC_RELEASE, __HIP_MEMORY_SCOPE_AGENT);
    } else {
      while (__hip_atomic_load(&bar[1], __ATOMIC_ACQUIRE, __HIP_MEMORY_SCOPE_AGENT) == g) {
        __builtin_amdgcn_s_sleep(2);
      }
    }
    __threadfence();
  }
  __syncthreads();
}

__global__ __launch_bounds__(256, 2) void k_step(
    const float* __restrict__ bH, const __half* __restrict__ Hp,
    const float* __restrict__ Wh2h, const float* __restrict__ bh2h,
    const float* __restrict__ Wsc,
    const float* __restrict__ Wih, const float* __restrict__ Whh,
    const float* __restrict__ bih, const float* __restrict__ bhh,
    const int* __restrict__ text,
    float* __restrict__ hid, float* __restrict__ cb,
    float* __restrict__ pp, float* __restrict__ ev, float* __restrict__ ctx,
    unsigned* __restrict__ bar) {
  __shared__ ShU sh;
  const int bid = blockIdx.x, tid = threadIdx.x;

  for (int t = 0; t < Tsz; ++t) {
    const float* hprev = hid + (size_t)t * Bsz * Hsz;
    float* hnext = hid + (size_t)(t + 1) * Bsz * Hsz;
    const float* cin = cb + (size_t)(t & 1) * Bsz * Hsz;
    float* cout = cb + (size_t)((t + 1) & 1) * Bsz * Hsz;

    // ---- phase 1: pp = hprev @ W_h2h^T + b ----
    {
      ShPP& P = sh.pp;
      int b = bid & 127, jq = bid >> 7;
      P.hs[tid] = hprev[b * Hsz + tid];
      P.hs[tid + 256] = hprev[b * Hsz + 256 + tid];
      __syncthreads();
      int jl = tid & 127, kh = tid >> 7;
      int j = jq * 128 + jl;
      const float* wrow = Wh2h + (size_t)j * Hsz + kh * 256;
      const float* hp = P.hs + kh * 256;
      float acc = 0.f;
#pragma unroll 4
      for (int k = 0; k < 256; k += 4) {
        float4 w = *(const float4*)(wrow + k);
        float4 h4 = *(const float4*)(hp + k);
        acc += w.x * h4.x + w.y * h4.y + w.z * h4.z + w.w * h4.w;
      }
      if (kh == 1) P.part[jl] = acc;
      __syncthreads();
      if (kh == 0) pp[b * Hsz + j] = acc + P.part[jl] + bh2h[j];
    }
    gridbar(bar);

    // ---- phase 2: e[b,s] = Wsc . tanh(Hp[b,s,:] + pp[b,:]) ----
    {
      ShE& E = sh.e;
      int b = bid >> 2, tile = bid & 3;
      for (int i = tid; i < 512; i += 256) {
        E.pps[i] = pp[b * Hsz + i];
        E.wss[i] = Wsc[i];
      }
      __syncthreads();
      int sl = tid & 127, kh = tid >> 7;
      int s = tile * 128 + sl;
      const __half* hrow = Hp + ((size_t)b * Ssz + s) * Hsz + kh * 256;
      const float* pk = E.pps + kh * 256;
      const float* wk = E.wss + kh * 256;
      float acc = 0.f;
#pragma unroll 4
      for (int k = 0; k < 256; k += 8) {
        float4 raw = *(const float4*)(hrow + k);
        const __half2* h2p = (const __half2*)&raw;
        float2 f0 = __half22float2(h2p[0]);
        float2 f1 = __half22float2(h2p[1]);
        float2 f2 = __half22float2(h2p[2]);
        float2 f3 = __half22float2(h2p[3]);
        acc += wk[k + 0] * fast_tanh(f0.x + pk[k + 0]);
        acc += wk[k + 1] * fast_tanh(f0.y + pk[k + 1]);
        acc += wk[k + 2] * fast_tanh(f1.x + pk[k + 2]);
        acc += wk[k + 3] * fast_tanh(f1.y + pk[k + 3]);
        acc += wk[k + 4] * fast_tanh(f2.x + pk[k + 4]);
        acc += wk[k + 5] * fast_tanh(f2.y + pk[k + 5]);
        acc += wk[k + 6] * fast_tanh(f3.x + pk[k + 6]);
        acc += wk[k + 7] * fast_tanh(f3.y + pk[k + 7]);
      }
      if (kh == 1) E.part[sl] = acc;
      __syncthreads();
      if (kh == 0) ev[b * Ssz + s] = acc + E.part[sl];
    }
    gridbar(bar);

    // ---- phase 3: softmax(e) then ctx = alpha @ batch_H ----
    {
      ShC& C = sh.c;
      int b = bid & 127, vq = bid >> 7;  // vq in [0,4): 150 v-cols per block
      int wv = tid >> 6, ln = tid & 63;
      float e0 = ev[b * Ssz + tid], e1 = ev[b * Ssz + 256 + tid];
      float m = fmaxf(e0, e1);
#pragma unroll
      for (int off = 32; off > 0; off >>= 1) m = fmaxf(m, __shfl_xor(m, off));
      if (ln == 0) C.wred[wv] = m;
      __syncthreads();
      m = fmaxf(fmaxf(C.wred[0], C.wred[1]), fmaxf(C.wred[2], C.wred[3]));
      float x0 = __expf(e0 - m), x1 = __expf(e1 - m);
      float sum = x0 + x1;
#pragma unroll
      for (int off = 32; off > 0; off >>= 1) sum += __shfl_xor(sum, off);
      if (ln == 0) C.wred[4 + wv] = sum;
      __syncthreads();
      sum = C.wred[4] + C.wred[5] + C.wred[6] + C.wred[7];
      float inv = __fdividef(1.f, sum);
      C.al[tid] = x0 * inv;
      C.al[tid + 256] = x1 * inv;
      __syncthreads();
      // dot: wave wv = s-group (s-chunks of 128); lane owns v = vq*150 + ln + {0,64,128}
      int sg = wv, vl = ln;
      const float* bp = bH + (size_t)b * Ssz * Vsz + (size_t)sg * 128 * Vsz + vq * 150 + vl;
      const float* ap = C.al + sg * 128;
      float a0 = 0.f, a1 = 0.f, a2 = 0.f;
      bool h2 = (vl < 22);  // vq*150 + vl + 128 < vq*150 + 150
#pragma unroll 8
      for (int s2 = 0; s2 < 128; ++s2) {
        float a = ap[s2];
        const float* r = bp + (size_t)s2 * Vsz;
        a0 += a * r[0];
        a1 += a * r[64];
        if (h2) a2 += a * r[128];
      }
      if (sg > 0) {
        C.part[sg - 1][0][vl] = a0;
        C.part[sg - 1][1][vl] = a1;
        C.part[sg - 1][2][vl] = a2;
      }
      __syncthreads();
      if (sg == 0) {
        a0 += C.part[0][0][vl] + C.part[1][0][vl] + C.part[2][0][vl];
        a1 += C.part[0][1][vl] + C.part[1][1][vl] + C.part[2][1][vl];
        a2 += C.part[0][2][vl] + C.part[1][2][vl] + C.part[2][2][vl];
        float* cp = ctx + b * Vsz + vq * 150 + vl;
        cp[0] = a0;
        cp[64] = a1;
        if (h2) cp[128] = a2;
      }
    }
    gridbar(bar);

    // ---- phase 4: gates + LSTM pointwise ----
    {
      ShG& G = sh.g;
      // XCD swizzle: all 32 b-tiles of a j-tile-pair land on one XCD (weights L2-resident)
      int jt = (bid & 7) * 2 + ((bid >> 3) & 1);  // [0,16)
      int bt = bid >> 4;                           // [0,32)
      int b0 = bt * 4, j0 = jt * 32;
      for (int idx = tid; idx < 4 * 600; idx += 256) {
        int r = idx / 600, k = idx - r * 600;
        G.xs[r][k] = ctx[(b0 + r) * Vsz + k];
      }
      for (int idx = tid; idx < 4 * 512; idx += 256) {
        int r = idx >> 9, k = idx & 511;
        G.xs[r][600 + k] = hprev[(b0 + r) * Hsz + k];
      }
      __syncthreads();
      int bi = tid >> 6;             // wave = batch row (LDS broadcast reads)
      int jl = tid & 31, kh = (tid >> 5) & 1;
      int b = b0 + bi, j = j0 + jl;
      float a0 = 0.f, a1 = 0.f, a2 = 0.f, a3 = 0.f;
      const float* xr = G.xs[bi];
      // ctx part: k in [kh*300, kh*300+300)
      const float* w0 = Wih + (size_t)(0 * Hsz + j) * 1200 + kh * 300;
      const float* w1 = Wih + (size_t)(1 * Hsz + j) * 1200 + kh * 300;
      const float* w2 = Wih + (size_t)(2 * Hsz + j) * 1200 + kh * 300;
      const float* w3 = Wih + (size_t)(3 * Hsz + j) * 1200 + kh * 300;
      const float* xc = xr + kh * 300;
#pragma unroll 2
      for (int k = 0; k < 300; k += 4) {
        float4 x4 = *(const float4*)(xc + k);
        float4 q0 = *(const float4*)(w0 + k);
        a0 += x4.x * q0.x + x4.y * q0.y + x4.z * q0.z + x4.w * q0.w;
        float4 q1 = *(const float4*)(w1 + k);
        a1 += x4.x * q1.x + x4.y * q1.y + x4.z * q1.z + x4.w * q1.w;
        float4 q2 = *(const float4*)(w2 + k);
        a2 += x4.x * q2.x + x4.y * q2.y + x4.z * q2.z + x4.w * q2.w;
        float4 q3 = *(const float4*)(w3 + k);
        a3 += x4.x * q3.x + x4.y * q3.y + x4.z * q3.z + x4.w * q3.w;
      }
      // h part: k in [kh*256, kh*256+256)
      const float* v0 = Whh + (size_t)(0 * Hsz + j) * Hsz + kh * 256;
      const float* v1 = Whh + (size_t)(1 * Hsz + j) * Hsz + kh * 256;
      const float* v2 = Whh + (size_t)(2 * Hsz + j) * Hsz + kh * 256;
      const float* v3 = Whh + (size_t)(3 * Hsz + j) * Hsz + kh * 256;
      const float* xh = xr + 600 + kh * 256;
#pragma unroll 2
      for (int k = 0; k < 256; k += 4) {
        float4 x4 = *(const float4*)(xh + k);
        float4 q0 = *(const float4*)(v0 + k);
        a0 += x4.x * q0.x + x4.y * q0.y + x4.z * q0.z + x4.w * q0.w;
        float4 q1 = *(const float4*)(v1 + k);
        a1 += x4.x * q1.x + x4.y * q1.y + x4.z * q1.z + x4.w * q1.w;
        float4 q2 = *(const float4*)(v2 + k);
        a2 += x4.x * q2.x + x4.y * q2.y + x4.z * q2.z + x4.w * q2.w;
        float4 q3 = *(const float4*)(v3 + k);
        a3 += x4.x * q3.x + x4.y * q3.y + x4.z * q3.z + x4.w * q3.w;
      }
      if (kh == 1) {
        int tk = (t == 0) ? 0 : text[b * Tsz + (t - 1)];
        a0 += Wih[(size_t)(0 * Hsz + j) * 1200 + 600 + tk];
        a1 += Wih[(size_t)(1 * Hsz + j) * 1200 + 600 + tk];
        a2 += Wih[(size_t)(2 * Hsz + j) * 1200 + 600 + tk];
        a3 += Wih[(size_t)(3 * Hsz + j) * 1200 + 600 + tk];
        G.part[bi][jl] = make_float4(a0, a1, a2, a3);
      }
      __syncthreads();
      if (kh == 0) {
        float4 p = G.part[bi][jl];
        a0 += p.x + bih[j] + bhh[j];
        a1 += p.y + bih[512 + j] + bhh[512 + j];
        a2 += p.z + bih[1024 + j] + bhh[1024 + j];
        a3 += p.w + bih[1536 + j] + bhh[1536 + j];
        float ig = 1.f / (1.f + __expf(-a0));
        float fg = 1.f / (1.f + __expf(-a1));
        float gg = fast_tanh(a2);
        float og = 1.f / (1.f + __expf(-a3));
        float c = fg * cin[b * Hsz + j] + ig * gg;
        float hN = og * fast_tanh(c);
        cout[b * Hsz + j] = c;
        hnext[b * Hsz + j] = hN;
      }
    }
    gridbar(bar);
  }
}

// ---------------- probs = softmax(hid @ W_gen^T + b_gen) ----------------
__global__ __launch_bounds__(256) void k_gen(const float* __restrict__ hid,
                                             const float* __restrict__ Wg,
                                             const float* __restrict__ bg,
                                             float* __restrict__ out) {
  __shared__ float sm[16 * 600];
  int m0 = blockIdx.x * 16;
  for (int idx = threadIdx.x; idx < 16 * 512; idx += 256) {
    int r = idx >> 9, k = idx & 511;
    int m = m0 + r;
    int bb = m / Tsz, tt = m - bb * Tsz;
    sm[r * 520 + k] = hid[((size_t)(tt + 1) * Bsz + bb) * Hsz + k];
  }
  __syncthreads();
  int rg = threadIdx.x & 3, cg = threadIdx.x >> 2;
  int r0 = rg * 4;
  bool has2 = (cg < 22);
  float acc[12][4] = {};
  for (int k = 0; k < 512; k += 4) {
    float4 a[4];
#pragma unroll
    for (int i = 0; i < 4; ++i) a[i] = *(const float4*)&sm[(r0 + i) * 520 + k];
#pragma unroll
    for (int p = 0; p < 3; ++p) {
      if (p == 2 && !has2) continue;
#pragma unroll
      for (int i = 0; i < 4; ++i) {
        int c = p * 256 + cg * 4 + i;
        float4 w = *(const float4*)&Wg[(size_t)c * Hsz + k];
        int ci = p * 4 + i;
#pragma unroll
        for (int r = 0; r < 4; ++r)
          acc[ci][r] += a[r].x * w.x + a[r].y * w.y + a[r].z * w.z + a[r].w * w.w;
      }
    }
  }
  __syncthreads();
#pragma unroll
  for (int p = 0; p < 3; ++p) {
    if (p == 2 && !has2) continue;
#pragma unroll
    for (int i = 0; i < 4; ++i) {
      int c = p * 256 + cg * 4 + i;
      float bgc = bg[c];
#pragma unroll
      for (int r = 0; r < 4; ++r) sm[(r0 + r) * 600 + c] = acc[p * 4 + i][r] + bgc;
    }
  }
  __syncthreads();
  int wv = threadIdx.x >> 6, ln = threadIdx.x & 63;
  for (int r = wv; r < 16; r += 4) {
    float* row = sm + r * 600;
    float mx = -1e30f;
    for (int c = ln; c < 600; c += 64) mx = fmaxf(mx, row[c]);
#pragma unroll
    for (int off = 32; off > 0; off >>= 1) mx = fmaxf(mx, __shfl_xor(mx, off));
    float ssum = 0.f;
    for (int c = ln; c < 600; c += 64) {
      float ex = __expf(row[c] - mx);
      row[c] = ex;
      ssum += ex;
    }
#pragma unroll
    for (int off = 32; off > 0; off >>= 1) ssum += __shfl_xor(ssum, off);
    float inv = __fdividef(1.f, ssum);
    float* op = out + (size_t)(m0 + r) * 600;
    for (int c = ln; c < 600; c += 64) op[c] = row[c] * inv;
  }
}

extern "C" void kernel_launch(void* const* d_in, const int* in_sizes, int n_in,
                              void* d_out, int out_size, void* d_ws, size_t ws_size,
                              hipStream_t stream) {
  const float* bH = (const float*)d_in[0];
  const int* text = (const int*)d_in[1];  // harness converts int64 -> int32
  const float* Wi2h = (const float*)d_in[2];
  const float* Wh2h = (const float*)d_in[3];
  const float* bh2h = (const float*)d_in[4];
  const float* Wsc = (const float*)d_in[5];
  const float* Wih = (const float*)d_in[6];
  const float* Whh = (const float*)d_in[7];
  const float* bih = (const float*)d_in[8];
  const float* bhh = (const float*)d_in[9];
  const float* Wg = (const float*)d_in[10];
  const float* bg = (const float*)d_in[11];
  float* out = (float*)d_out;

  float* ws = (float*)d_ws;
  size_t off = 0;
  __half* Hp = (__half*)(ws + off); off += (size_t)Bsz * Ssz * Hsz;  // region kept float-sized
  float* hid = ws + off; off += (size_t)(Tsz + 1) * Bsz * Hsz;
  float* cb = ws + off;  off += (size_t)2 * Bsz * Hsz;
  float* pp = ws + off;  off += (size_t)Bsz * Hsz;
  float* ev = ws + off;  off += (size_t)Bsz * Ssz;
  float* ctx = ws + off; off += (size_t)Bsz * Vsz;
  off += 64;  // pad to isolate barrier cacheline
  unsigned* bar = (unsigned*)(ws + off);

  hipMemsetAsync(hid, 0, (size_t)Bsz * Hsz * sizeof(float), stream);  // h0 = 0
  hipMemsetAsync(cb, 0, (size_t)Bsz * Hsz * sizeof(float), stream);   // c0 = 0
  hipMemsetAsync(bar, 0, 2 * sizeof(unsigned), stream);               // barrier state

  k_hp<<<(Bsz * Ssz) / 16, 256, 0, stream>>>(bH, Wi2h, Hp);
  k_step<<<NBLK, 256, 0, stream>>>(bH, Hp, Wh2h, bh2h, Wsc, Wih, Whh, bih, bhh,
                                   text, hid, cb, pp, ev, ctx, bar);
  k_gen<<<(Bsz * Tsz) / 16, 256, 0, stream>>>(hid, Wg, bg, out);
}

// Round 5
// 44952.341 us; speedup vs baseline: 2.6052x; 2.6052x over previous
//
#include <hip/hip_runtime.h>
#include <hip/hip_fp16.h>
#include <stdint.h>

#define Bsz 128
#define Ssz 512
#define Vsz 600
#define Hsz 512
#define Tsz 121
#define NBLK 512
#define FSTR 32  // flag stride in u32 (128 B per flag line)

// branch-free 6-op tanh: tanh(x) = 1 - 2/(1 + e^{2x}); exact at +/-inf, ~1e-6 abs err
__device__ __forceinline__ float fast_tanh(float x) {
  float e = __expf(x + x);
  return 1.0f - __fdividef(2.0f, 1.0f + e);
}

// ---------------- H_proj(fp16) = batch_H @ W_i2h^T ----------------
__global__ __launch_bounds__(256) void k_hp(const float* __restrict__ bH,
                                            const float* __restrict__ Wi,
                                            __half* __restrict__ Hp) {
  __shared__ float As[16][604];
  int m0 = blockIdx.x * 16;
  for (int idx = threadIdx.x; idx < 16 * 600; idx += 256) {
    int r = idx / 600, k = idx - r * 600;
    As[r][k] = bH[(size_t)(m0 + r) * 600 + k];
  }
  __syncthreads();
  int rg = threadIdx.x & 3, cg = threadIdx.x >> 2;
  int r0 = rg * 4;
  for (int pass = 0; pass < 2; ++pass) {
    int c0 = pass * 256 + cg * 4;
    float acc[4][4] = {};
    const float* w0p = Wi + (size_t)(c0 + 0) * 600;
    const float* w1p = Wi + (size_t)(c0 + 1) * 600;
    const float* w2p = Wi + (size_t)(c0 + 2) * 600;
    const float* w3p = Wi + (size_t)(c0 + 3) * 600;
    for (int k = 0; k < 600; k += 4) {
      float4 w0 = *(const float4*)(w0p + k);
      float4 w1 = *(const float4*)(w1p + k);
      float4 w2 = *(const float4*)(w2p + k);
      float4 w3 = *(const float4*)(w3p + k);
#pragma unroll
      for (int i = 0; i < 4; ++i) {
        float4 a = *(const float4*)&As[r0 + i][k];
        acc[i][0] += a.x * w0.x + a.y * w0.y + a.z * w0.z + a.w * w0.w;
        acc[i][1] += a.x * w1.x + a.y * w1.y + a.z * w1.z + a.w * w1.w;
        acc[i][2] += a.x * w2.x + a.y * w2.y + a.z * w2.z + a.w * w2.w;
        acc[i][3] += a.x * w3.x + a.y * w3.y + a.z * w3.z + a.w * w3.w;
      }
    }
#pragma unroll
    for (int i = 0; i < 4; ++i) {
      __half2 p01 = __floats2half2_rn(acc[i][0], acc[i][1]);
      __half2 p23 = __floats2half2_rn(acc[i][2], acc[i][3]);
      union { __half2 h2[2]; float2 f2; } u;
      u.h2[0] = p01; u.h2[1] = p23;
      *(float2*)&Hp[(size_t)(m0 + r0 + i) * Hsz + c0] = u.f2;
    }
  }
}

// ---------------- persistent step loop with per-b flag sync ----------------
struct ShPP { float hs[512]; float part[128]; };
struct ShE  { float pps[512]; float wss[512]; float part[128]; };
struct ShC  { float al[512]; float wred[8]; float part[3][3][64]; };
struct ShG  { float xs[4][1112]; float4 part[4][32]; };
union ShU { ShPP pp; ShE e; ShC c; ShG g; };

__device__ __forceinline__ void flag_wait1(unsigned* f, unsigned tgt) {
  if (threadIdx.x == 0) {
    while (__hip_atomic_load(f, __ATOMIC_ACQUIRE, __HIP_MEMORY_SCOPE_AGENT) < tgt)
      __builtin_amdgcn_s_sleep(16);
  }
  __syncthreads();
}
__device__ __forceinline__ void flag_bump(unsigned* f) {
  __syncthreads();  // all block stores issued & drained (vmcnt(0) before barrier)
  if (threadIdx.x == 0)
    __hip_atomic_fetch_add(f, 1u, __ATOMIC_RELEASE, __HIP_MEMORY_SCOPE_AGENT);
}

__global__ __launch_bounds__(256, 2) void k_step(
    const float* __restrict__ bH, const __half* __restrict__ Hp,
    const float* __restrict__ Wh2h, const float* __restrict__ bh2h,
    const float* __restrict__ Wsc,
    const float* __restrict__ Wih, const float* __restrict__ Whh,
    const float* __restrict__ bih, const float* __restrict__ bhh,
    const int* __restrict__ text,
    float* __restrict__ hid, float* __restrict__ pp,
    float* __restrict__ ev, float* __restrict__ ctx,
    unsigned* __restrict__ flags) {
  __shared__ ShU sh;
  const int bid = blockIdx.x, tid = threadIdx.x;
  unsigned* ppf = flags;
  unsigned* evf = flags + 128 * FSTR;
  unsigned* ctf = flags + 256 * FSTR;
  unsigned* hf  = flags + 384 * FSTR;
  const int b = bid >> 2, q = bid & 3;            // P/E/C roles
  const int bt = bid >> 4;                         // G role: 4 b's
  const int jt = (bid & 7) * 2 + ((bid >> 3) & 1); // XCD-grouped j-tile
  float c_reg = 0.f;                               // LSTM cell state (kh==0 lanes)

  for (int t = 0; t < Tsz; ++t) {
    const float* hprev = hid + (size_t)t * Bsz * Hsz;
    float* hnext = hid + (size_t)(t + 1) * Bsz * Hsz;

    // ---- P: pp[b, q*128..] = hprev[b] @ W_h2h^T + b_h2h ----
    {
      if (t == 0) {
        if (tid < 128) pp[b * Hsz + q * 128 + tid] = bh2h[q * 128 + tid];
      } else {
        flag_wait1(hf + (size_t)(b >> 2) * FSTR, 16u * (unsigned)t);
        ShPP& P = sh.pp;
        P.hs[tid] = hprev[b * Hsz + tid];
        P.hs[tid + 256] = hprev[b * Hsz + 256 + tid];
        __syncthreads();
        int jl = tid & 127, kh = tid >> 7;
        int j = q * 128 + jl;
        const float* wrow = Wh2h + (size_t)j * Hsz + kh * 256;
        const float* hp = P.hs + kh * 256;
        float acc = 0.f;
#pragma unroll 4
        for (int k = 0; k < 256; k += 4) {
          float4 w = *(const float4*)(wrow + k);
          float4 h4 = *(const float4*)(hp + k);
          acc += w.x * h4.x + w.y * h4.y + w.z * h4.z + w.w * h4.w;
        }
        if (kh == 1) P.part[jl] = acc;
        __syncthreads();
        if (kh == 0) pp[b * Hsz + j] = acc + P.part[jl] + bh2h[j];
      }
      flag_bump(ppf + (size_t)b * FSTR);
    }

    // ---- E: e[b, q*128..] = Wsc . tanh(Hp + pp) ----
    {
      flag_wait1(ppf + (size_t)b * FSTR, 4u * (unsigned)(t + 1));
      ShE& E = sh.e;
      for (int i = tid; i < 512; i += 256) {
        E.pps[i] = pp[b * Hsz + i];
        E.wss[i] = Wsc[i];
      }
      __syncthreads();
      int sl = tid & 127, kh = tid >> 7;
      int s = q * 128 + sl;
      const __half* hrow = Hp + ((size_t)b * Ssz + s) * Hsz + kh * 256;
      const float* pk = E.pps + kh * 256;
      const float* wk = E.wss + kh * 256;
      float acc = 0.f;
#pragma unroll 4
      for (int k = 0; k < 256; k += 8) {
        float4 raw = *(const float4*)(hrow + k);
        const __half2* h2p = (const __half2*)&raw;
        float2 f0 = __half22float2(h2p[0]);
        float2 f1 = __half22float2(h2p[1]);
        float2 f2 = __half22float2(h2p[2]);
        float2 f3 = __half22float2(h2p[3]);
        acc += wk[k + 0] * fast_tanh(f0.x + pk[k + 0]);
        acc += wk[k + 1] * fast_tanh(f0.y + pk[k + 1]);
        acc += wk[k + 2] * fast_tanh(f1.x + pk[k + 2]);
        acc += wk[k + 3] * fast_tanh(f1.y + pk[k + 3]);
        acc += wk[k + 4] * fast_tanh(f2.x + pk[k + 4]);
        acc += wk[k + 5] * fast_tanh(f2.y + pk[k + 5]);
        acc += wk[k + 6] * fast_tanh(f3.x + pk[k + 6]);
        acc += wk[k + 7] * fast_tanh(f3.y + pk[k + 7]);
      }
      if (kh == 1) E.part[sl] = acc;
      __syncthreads();
      if (kh == 0) ev[b * Ssz + s] = acc + E.part[sl];
      flag_bump(evf + (size_t)b * FSTR);
    }

    // ---- C: softmax(e[b]) then ctx[b, q*150..] = alpha @ batch_H ----
    {
      flag_wait1(evf + (size_t)b * FSTR, 4u * (unsigned)(t + 1));
      ShC& C = sh.c;
      int wv = tid >> 6, ln = tid & 63;
      float e0 = ev[b * Ssz + tid], e1 = ev[b * Ssz + 256 + tid];
      float m = fmaxf(e0, e1);
#pragma unroll
      for (int off = 32; off > 0; off >>= 1) m = fmaxf(m, __shfl_xor(m, off));
      if (ln == 0) C.wred[wv] = m;
      __syncthreads();
      m = fmaxf(fmaxf(C.wred[0], C.wred[1]), fmaxf(C.wred[2], C.wred[3]));
      float x0 = __expf(e0 - m), x1 = __expf(e1 - m);
      float sum = x0 + x1;
#pragma unroll
      for (int off = 32; off > 0; off >>= 1) sum += __shfl_xor(sum, off);
      if (ln == 0) C.wred[4 + wv] = sum;
      __syncthreads();
      sum = C.wred[4] + C.wred[5] + C.wred[6] + C.wred[7];
      float inv = __fdividef(1.f, sum);
      C.al[tid] = x0 * inv;
      C.al[tid + 256] = x1 * inv;
      __syncthreads();
      int sg = wv, vl = ln;
      const float* bp = bH + (size_t)b * Ssz * Vsz + (size_t)sg * 128 * Vsz + q * 150 + vl;
      const float* ap = C.al + sg * 128;
      float a0 = 0.f, a1 = 0.f, a2 = 0.f;
      bool h2 = (vl < 22);
#pragma unroll 8
      for (int s2 = 0; s2 < 128; ++s2) {
        float a = ap[s2];
        const float* r = bp + (size_t)s2 * Vsz;
        a0 += a * r[0];
        a1 += a * r[64];
        if (h2) a2 += a * r[128];
      }
      if (sg > 0) {
        C.part[sg - 1][0][vl] = a0;
        C.part[sg - 1][1][vl] = a1;
        C.part[sg - 1][2][vl] = a2;
      }
      __syncthreads();
      if (sg == 0) {
        a0 += C.part[0][0][vl] + C.part[1][0][vl] + C.part[2][0][vl];
        a1 += C.part[0][1][vl] + C.part[1][1][vl] + C.part[2][1][vl];
        a2 += C.part[0][2][vl] + C.part[1][2][vl] + C.part[2][2][vl];
        float* cp = ctx + b * Vsz + q * 150 + vl;
        cp[0] = a0;
        cp[64] = a1;
        if (h2) cp[128] = a2;
      }
      flag_bump(ctf + (size_t)b * FSTR);
    }

    // ---- G: gates + LSTM pointwise for (bt: 4 b's) x (jt: 32 j's) ----
    {
      unsigned tgt = 4u * (unsigned)(t + 1);
      if (tid < 4) {
        unsigned* f = ctf + (size_t)(bt * 4 + tid) * FSTR;
        while (__hip_atomic_load(f, __ATOMIC_ACQUIRE, __HIP_MEMORY_SCOPE_AGENT) < tgt)
          __builtin_amdgcn_s_sleep(16);
      }
      __syncthreads();
      ShG& G = sh.g;
      int b0 = bt * 4, j0 = jt * 32;
      for (int idx = tid; idx < 4 * 600; idx += 256) {
        int r = idx / 600, k = idx - r * 600;
        G.xs[r][k] = ctx[(b0 + r) * Vsz + k];
      }
      for (int idx = tid; idx < 4 * 512; idx += 256) {
        int r = idx >> 9, k = idx & 511;
        G.xs[r][600 + k] = (t == 0) ? 0.f : hprev[(b0 + r) * Hsz + k];
      }
      __syncthreads();
      int bi = tid >> 6, jl = tid & 31, kh = (tid >> 5) & 1;
      int bb = b0 + bi, j = j0 + jl;
      float a0 = 0.f, a1 = 0.f, a2 = 0.f, a3 = 0.f;
      const float* xr = G.xs[bi];
      const float* w0 = Wih + (size_t)(0 * Hsz + j) * 1200 + kh * 300;
      const float* w1 = Wih + (size_t)(1 * Hsz + j) * 1200 + kh * 300;
      const float* w2 = Wih + (size_t)(2 * Hsz + j) * 1200 + kh * 300;
      const float* w3 = Wih + (size_t)(3 * Hsz + j) * 1200 + kh * 300;
      const float* xc = xr + kh * 300;
#pragma unroll 2
      for (int k = 0; k < 300; k += 4) {
        float4 x4 = *(const float4*)(xc + k);
        float4 q0 = *(const float4*)(w0 + k);
        a0 += x4.x * q0.x + x4.y * q0.y + x4.z * q0.z + x4.w * q0.w;
        float4 q1 = *(const float4*)(w1 + k);
        a1 += x4.x * q1.x + x4.y * q1.y + x4.z * q1.z + x4.w * q1.w;
        float4 q2 = *(const float4*)(w2 + k);
        a2 += x4.x * q2.x + x4.y * q2.y + x4.z * q2.z + x4.w * q2.w;
        float4 q3 = *(const float4*)(w3 + k);
        a3 += x4.x * q3.x + x4.y * q3.y + x4.z * q3.z + x4.w * q3.w;
      }
      const float* v0 = Whh + (size_t)(0 * Hsz + j) * Hsz + kh * 256;
      const float* v1 = Whh + (size_t)(1 * Hsz + j) * Hsz + kh * 256;
      const float* v2 = Whh + (size_t)(2 * Hsz + j) * Hsz + kh * 256;
      const float* v3 = Whh + (size_t)(3 * Hsz + j) * Hsz + kh * 256;
      const float* xh = xr + 600 + kh * 256;
#pragma unroll 2
      for (int k = 0; k < 256; k += 4) {
        float4 x4 = *(const float4*)(xh + k);
        float4 q0 = *(const float4*)(v0 + k);
        a0 += x4.x * q0.x + x4.y * q0.y + x4.z * q0.z + x4.w * q0.w;
        float4 q1 = *(const float4*)(v1 + k);
        a1 += x4.x * q1.x + x4.y * q1.y + x4.z * q1.z + x4.w * q1.w;
        float4 q2 = *(const float4*)(v2 + k);
        a2 += x4.x * q2.x + x4.y * q2.y + x4.z * q2.z + x4.w * q2.w;
        float4 q3 = *(const float4*)(v3 + k);
        a3 += x4.x * q3.x + x4.y * q3.y + x4.z * q3.z + x4.w * q3.w;
      }
      if (kh == 1) {
        int tk = (t == 0) ? 0 : text[bb * Tsz + (t - 1)];
        a0 += Wih[(size_t)(0 * Hsz + j) * 1200 + 600 + tk];
        a1 += Wih[(size_t)(1 * Hsz + j) * 1200 + 600 + tk];
        a2 += Wih[(size_t)(2 * Hsz + j) * 1200 + 600 + tk];
        a3 += Wih[(size_t)(3 * Hsz + j) * 1200 + 600 + tk];
        G.part[bi][jl] = make_float4(a0, a1, a2, a3);
      }
      __syncthreads();
      if (kh == 0) {
        float4 p = G.part[bi][jl];
        a0 += p.x + bih[j] + bhh[j];
        a1 += p.y + bih[512 + j] + bhh[512 + j];
        a2 += p.z + bih[1024 + j] + bhh[1024 + j];
        a3 += p.w + bih[1536 + j] + bhh[1536 + j];
        float ig = 1.f / (1.f + __expf(-a0));
        float fg = 1.f / (1.f + __expf(-a1));
        float gg = fast_tanh(a2);
        float og = 1.f / (1.f + __expf(-a3));
        c_reg = fg * c_reg + ig * gg;
        hnext[bb * Hsz + j] = og * fast_tanh(c_reg);
      }
      flag_bump(hf + (size_t)bt * FSTR);
    }
  }
}

// ---------------- probs = softmax(hid @ W_gen^T + b_gen) ----------------
__global__ __launch_bounds__(256) void k_gen(const float* __restrict__ hid,
                                             const float* __restrict__ Wg,
                                             const float* __restrict__ bg,
                                             float* __restrict__ out) {
  __shared__ float sm[16 * 600];
  int m0 = blockIdx.x * 16;
  for (int idx = threadIdx.x; idx < 16 * 512; idx += 256) {
    int r = idx >> 9, k = idx & 511;
    int m = m0 + r;
    int bb = m / Tsz, tt = m - bb * Tsz;
    sm[r * 520 + k] = hid[((size_t)(tt + 1) * Bsz + bb) * Hsz + k];
  }
  __syncthreads();
  int rg = threadIdx.x & 3, cg = threadIdx.x >> 2;
  int r0 = rg * 4;
  bool has2 = (cg < 22);
  float acc[12][4] = {};
  for (int k = 0; k < 512; k += 4) {
    float4 a[4];
#pragma unroll
    for (int i = 0; i < 4; ++i) a[i] = *(const float4*)&sm[(r0 + i) * 520 + k];
#pragma unroll
    for (int p = 0; p < 3; ++p) {
      if (p == 2 && !has2) continue;
#pragma unroll
      for (int i = 0; i < 4; ++i) {
        int c = p * 256 + cg * 4 + i;
        float4 w = *(const float4*)&Wg[(size_t)c * Hsz + k];
        int ci = p * 4 + i;
#pragma unroll
        for (int r = 0; r < 4; ++r)
          acc[ci][r] += a[r].x * w.x + a[r].y * w.y + a[r].z * w.z + a[r].w * w.w;
      }
    }
  }
  __syncthreads();
#pragma unroll
  for (int p = 0; p < 3; ++p) {
    if (p == 2 && !has2) continue;
#pragma unroll
    for (int i = 0; i < 4; ++i) {
      int c = p * 256 + cg * 4 + i;
      float bgc = bg[c];
#pragma unroll
      for (int r = 0; r < 4; ++r) sm[(r0 + r) * 600 + c] = acc[p * 4 + i][r] + bgc;
    }
  }
  __syncthreads();
  int wv = threadIdx.x >> 6, ln = threadIdx.x & 63;
  for (int r = wv; r < 16; r += 4) {
    float* row = sm + r * 600;
    float mx = -1e30f;
    for (int c = ln; c < 600; c += 64) mx = fmaxf(mx, row[c]);
#pragma unroll
    for (int off = 32; off > 0; off >>= 1) mx = fmaxf(mx, __shfl_xor(mx, off));
    float ssum = 0.f;
    for (int c = ln; c < 600; c += 64) {
      float ex = __expf(row[c] - mx);
      row[c] = ex;
      ssum += ex;
    }
#pragma unroll
    for (int off = 32; off > 0; off >>= 1) ssum += __shfl_xor(ssum, off);
    float inv = __fdividef(1.f, ssum);
    float* op = out + (size_t)(m0 + r) * 600;
    for (int c = ln; c < 600; c += 64) op[c] = row[c] * inv;
  }
}

extern "C" void kernel_launch(void* const* d_in, const int* in_sizes, int n_in,
                              void* d_out, int out_size, void* d_ws, size_t ws_size,
                              hipStream_t stream) {
  const float* bH = (const float*)d_in[0];
  const int* text = (const int*)d_in[1];  // harness converts int64 -> int32
  const float* Wi2h = (const float*)d_in[2];
  const float* Wh2h = (const float*)d_in[3];
  const float* bh2h = (const float*)d_in[4];
  const float* Wsc = (const float*)d_in[5];
  const float* Wih = (const float*)d_in[6];
  const float* Whh = (const float*)d_in[7];
  const float* bih = (const float*)d_in[8];
  const float* bhh = (const float*)d_in[9];
  const float* Wg = (const float*)d_in[10];
  const float* bg = (const float*)d_in[11];
  float* out = (float*)d_out;

  float* ws = (float*)d_ws;
  size_t off = 0;
  __half* Hp = (__half*)(ws + off); off += (size_t)Bsz * Ssz * Hsz;  // float-sized region
  float* hid = ws + off; off += (size_t)(Tsz + 1) * Bsz * Hsz;
  float* pp = ws + off;  off += (size_t)Bsz * Hsz;
  float* ev = ws + off;  off += (size_t)Bsz * Ssz;
  float* ctx = ws + off; off += (size_t)Bsz * Vsz;
  off += 64;  // isolate flag region
  unsigned* flags = (unsigned*)(ws + off);  // 416 lines x 128 B

  hipMemsetAsync(flags, 0, (size_t)416 * FSTR * sizeof(unsigned), stream);

  k_hp<<<(Bsz * Ssz) / 16, 256, 0, stream>>>(bH, Wi2h, Hp);
  k_step<<<NBLK, 256, 0, stream>>>(bH, Hp, Wh2h, bh2h, Wsc, Wih, Whh, bih, bhh,
                                   text, hid, pp, ev, ctx, flags);
  k_gen<<<(Bsz * Tsz) / 16, 256, 0, stream>>>(hid, Wg, bg, out);
}

// Round 6
// 33501.709 us; speedup vs baseline: 3.4957x; 1.3418x over previous
//
#include <hip/hip_runtime.h>
#include <hip/hip_fp16.h>
#include <stdint.h>

#define Bsz 128
#define Ssz 512
#define Vsz 600
#define Hsz 512
#define Tsz 121

// branch-free 6-op tanh: tanh(x) = 1 - 2/(1 + e^{2x}); exact at +/-inf, ~1e-6 abs err
__device__ __forceinline__ float fast_tanh(float x) {
  float e = __expf(x + x);
  return 1.0f - __fdividef(2.0f, 1.0f + e);
}

// ---------------- one-time: Hp16 = (batch_H @ W_i2h^T) fp16,  bHT = batch_H^T fp16 ----------------
__global__ __launch_bounds__(256) void k_hp(const float* __restrict__ bH,
                                            const float* __restrict__ Wi,
                                            __half* __restrict__ Hp,
                                            __half* __restrict__ bHT) {
  __shared__ __align__(16) float As[16][604];
  int m0 = blockIdx.x * 16;
  for (int idx = threadIdx.x; idx < 16 * 600; idx += 256) {
    int r = idx / 600, k = idx - r * 600;
    As[r][k] = bH[(size_t)(m0 + r) * 600 + k];
  }
  __syncthreads();
  // transposed fp16 copy: bHT[b][v][s0..s0+15]
  {
    int b = blockIdx.x >> 5, s0 = (blockIdx.x & 31) * 16;
    for (int v = threadIdx.x; v < 600; v += 256) {
      __half hbuf[16];
#pragma unroll
      for (int r = 0; r < 16; ++r) hbuf[r] = __float2half(As[r][v]);
      float4* dst = (float4*)&bHT[((size_t)b * 600 + v) * 512 + s0];
      dst[0] = ((float4*)hbuf)[0];
      dst[1] = ((float4*)hbuf)[1];
    }
  }
  int rg = threadIdx.x & 3, cg = threadIdx.x >> 2;
  int r0 = rg * 4;
  for (int pass = 0; pass < 2; ++pass) {
    int c0 = pass * 256 + cg * 4;
    float acc[4][4] = {};
    const float* w0p = Wi + (size_t)(c0 + 0) * 600;
    const float* w1p = Wi + (size_t)(c0 + 1) * 600;
    const float* w2p = Wi + (size_t)(c0 + 2) * 600;
    const float* w3p = Wi + (size_t)(c0 + 3) * 600;
    for (int k = 0; k < 600; k += 4) {
      float4 w0 = *(const float4*)(w0p + k);
      float4 w1 = *(const float4*)(w1p + k);
      float4 w2 = *(const float4*)(w2p + k);
      float4 w3 = *(const float4*)(w3p + k);
#pragma unroll
      for (int i = 0; i < 4; ++i) {
        float4 a = *(const float4*)&As[r0 + i][k];
        acc[i][0] += a.x * w0.x + a.y * w0.y + a.z * w0.z + a.w * w0.w;
        acc[i][1] += a.x * w1.x + a.y * w1.y + a.z * w1.z + a.w * w1.w;
        acc[i][2] += a.x * w2.x + a.y * w2.y + a.z * w2.z + a.w * w2.w;
        acc[i][3] += a.x * w3.x + a.y * w3.y + a.z * w3.z + a.w * w3.w;
      }
    }
#pragma unroll
    for (int i = 0; i < 4; ++i) {
      __half2 p01 = __floats2half2_rn(acc[i][0], acc[i][1]);
      __half2 p23 = __floats2half2_rn(acc[i][2], acc[i][3]);
      union { __half2 h2[2]; float2 f2; } u;
      u.h2[0] = p01; u.h2[1] = p23;
      *(float2*)&Hp[(size_t)(m0 + r0 + i) * Hsz + c0] = u.f2;
    }
  }
}

// ---------------- per step: attention chain, one block per batch element ----------------
// 128 blocks x 512 threads: pp (LDS) -> e (LDS) -> softmax (LDS) -> ctx (global)
__global__ __launch_bounds__(512) void k_att(const __half* __restrict__ bHT,
                                             const __half* __restrict__ Hp,
                                             const float* __restrict__ Wh2h,
                                             const float* __restrict__ bh2h,
                                             const float* __restrict__ Wsc,
                                             const float* __restrict__ hprev,
                                             float* __restrict__ ctx) {
  __shared__ __align__(16) float hs[512];
  __shared__ __align__(16) float pps[512];
  __shared__ __align__(16) float wss[512];
  __shared__ __align__(16) float al[512];
  __shared__ float red[16];
  const int b = blockIdx.x, tid = threadIdx.x;

  hs[tid] = hprev[b * Hsz + tid];
  wss[tid] = Wsc[tid];
  __syncthreads();

  // pp[j] = b_h2h[j] + h . W_h2h[j,:]
  {
    const float* wrow = Wh2h + (size_t)tid * Hsz;
    float acc = bh2h[tid];
#pragma unroll 4
    for (int k = 0; k < Hsz; k += 4) {
      float4 w = *(const float4*)(wrow + k);
      float4 h4 = *(const float4*)&hs[k];
      acc += w.x * h4.x + w.y * h4.y + w.z * h4.z + w.w * h4.w;
    }
    pps[tid] = acc;
  }
  __syncthreads();

  // e[s] = sum_k wss[k] * tanh(Hp[b,s,k] + pps[k])
  float e;
  {
    const __half* hrow = Hp + ((size_t)b * Ssz + tid) * Hsz;
    float acc = 0.f;
#pragma unroll 2
    for (int k = 0; k < Hsz; k += 8) {
      float4 raw = *(const float4*)(hrow + k);
      const __half2* h2p = (const __half2*)&raw;
      float2 f0 = __half22float2(h2p[0]);
      float2 f1 = __half22float2(h2p[1]);
      float2 f2 = __half22float2(h2p[2]);
      float2 f3 = __half22float2(h2p[3]);
      acc += wss[k + 0] * fast_tanh(f0.x + pps[k + 0]);
      acc += wss[k + 1] * fast_tanh(f0.y + pps[k + 1]);
      acc += wss[k + 2] * fast_tanh(f1.x + pps[k + 2]);
      acc += wss[k + 3] * fast_tanh(f1.y + pps[k + 3]);
      acc += wss[k + 4] * fast_tanh(f2.x + pps[k + 4]);
      acc += wss[k + 5] * fast_tanh(f2.y + pps[k + 5]);
      acc += wss[k + 6] * fast_tanh(f3.x + pps[k + 6]);
      acc += wss[k + 7] * fast_tanh(f3.y + pps[k + 7]);
    }
    e = acc;
  }

  // softmax over the 512 threads (8 waves)
  int wv = tid >> 6, ln = tid & 63;
  float m = e;
#pragma unroll
  for (int off = 32; off > 0; off >>= 1) m = fmaxf(m, __shfl_xor(m, off));
  if (ln == 0) red[wv] = m;
  __syncthreads();
  m = fmaxf(fmaxf(fmaxf(red[0], red[1]), fmaxf(red[2], red[3])),
            fmaxf(fmaxf(red[4], red[5]), fmaxf(red[6], red[7])));
  float x = __expf(e - m);
  float sum = x;
#pragma unroll
  for (int off = 32; off > 0; off >>= 1) sum += __shfl_xor(sum, off);
  if (ln == 0) red[8 + wv] = sum;
  __syncthreads();
  sum = (red[8] + red[9]) + (red[10] + red[11]) +
        (red[12] + red[13]) + (red[14] + red[15]);
  al[tid] = x * __fdividef(1.f, sum);
  __syncthreads();

  // ctx[v] = sum_s al[s] * bHT[b,v,s]
  for (int v = tid; v < Vsz; v += 512) {
    const __half* brow = bHT + ((size_t)b * Vsz + v) * Ssz;
    float a0 = 0.f, a1 = 0.f, a2 = 0.f, a3 = 0.f;
#pragma unroll 2
    for (int s = 0; s < Ssz; s += 8) {
      float4 raw = *(const float4*)(brow + s);
      const __half2* h2p = (const __half2*)&raw;
      float2 f0 = __half22float2(h2p[0]);
      float2 f1 = __half22float2(h2p[1]);
      float2 f2 = __half22float2(h2p[2]);
      float2 f3 = __half22float2(h2p[3]);
      float4 a4a = *(const float4*)&al[s];
      float4 a4b = *(const float4*)&al[s + 4];
      a0 += a4a.x * f0.x + a4a.y * f0.y;
      a1 += a4a.z * f1.x + a4a.w * f1.y;
      a2 += a4b.x * f2.x + a4b.y * f2.y;
      a3 += a4b.z * f3.x + a4b.w * f3.y;
    }
    ctx[b * Vsz + v] = (a0 + a1) + (a2 + a3);
  }
}

// ---------------- per step: gates + LSTM pointwise ----------------
// 512 blocks x 256 thr: bt = 4 b's, jt = 32 j's (XCD-grouped), kh split x2
struct ShG { float xs[4][1112]; float4 part[4][32]; };

__global__ __launch_bounds__(256) void k_gates(
    const float* __restrict__ ctx, const float* __restrict__ hprev,
    const float* __restrict__ Wih, const float* __restrict__ Whh,
    const float* __restrict__ bih, const float* __restrict__ bhh,
    const int* __restrict__ text, int t,
    const float* __restrict__ cin, float* __restrict__ cout,
    float* __restrict__ hnextf, __half* __restrict__ hnext16) {
  __shared__ __align__(16) ShG G;
  const int bid = blockIdx.x, tid = threadIdx.x;
  const int jt = (bid & 7) * 2 + ((bid >> 3) & 1);  // XCD d%8 owns 2 j-tiles
  const int bt = bid >> 4;
  int b0 = bt * 4, j0 = jt * 32;
  for (int idx = tid; idx < 4 * 600; idx += 256) {
    int r = idx / 600, k = idx - r * 600;
    G.xs[r][k] = ctx[(b0 + r) * Vsz + k];
  }
  for (int idx = tid; idx < 4 * 512; idx += 256) {
    int r = idx >> 9, k = idx & 511;
    G.xs[r][600 + k] = hprev[(b0 + r) * Hsz + k];
  }
  __syncthreads();
  int bi = tid >> 6, jl = tid & 31, kh = (tid >> 5) & 1;
  int bb = b0 + bi, j = j0 + jl;
  float a0 = 0.f, a1 = 0.f, a2 = 0.f, a3 = 0.f;
  const float* xr = G.xs[bi];
  const float* w0 = Wih + (size_t)(0 * Hsz + j) * 1200 + kh * 300;
  const float* w1 = Wih + (size_t)(1 * Hsz + j) * 1200 + kh * 300;
  const float* w2 = Wih + (size_t)(2 * Hsz + j) * 1200 + kh * 300;
  const float* w3 = Wih + (size_t)(3 * Hsz + j) * 1200 + kh * 300;
  const float* xc = xr + kh * 300;
#pragma unroll 2
  for (int k = 0; k < 300; k += 4) {
    float4 x4 = *(const float4*)(xc + k);
    float4 q0 = *(const float4*)(w0 + k);
    a0 += x4.x * q0.x + x4.y * q0.y + x4.z * q0.z + x4.w * q0.w;
    float4 q1 = *(const float4*)(w1 + k);
    a1 += x4.x * q1.x + x4.y * q1.y + x4.z * q1.z + x4.w * q1.w;
    float4 q2 = *(const float4*)(w2 + k);
    a2 += x4.x * q2.x + x4.y * q2.y + x4.z * q2.z + x4.w * q2.w;
    float4 q3 = *(const float4*)(w3 + k);
    a3 += x4.x * q3.x + x4.y * q3.y + x4.z * q3.z + x4.w * q3.w;
  }
  const float* v0 = Whh + (size_t)(0 * Hsz + j) * Hsz + kh * 256;
  const float* v1 = Whh + (size_t)(1 * Hsz + j) * Hsz + kh * 256;
  const float* v2 = Whh + (size_t)(2 * Hsz + j) * Hsz + kh * 256;
  const float* v3 = Whh + (size_t)(3 * Hsz + j) * Hsz + kh * 256;
  const float* xh = xr + 600 + kh * 256;
#pragma unroll 2
  for (int k = 0; k < 256; k += 4) {
    float4 x4 = *(const float4*)(xh + k);
    float4 q0 = *(const float4*)(v0 + k);
    a0 += x4.x * q0.x + x4.y * q0.y + x4.z * q0.z + x4.w * q0.w;
    float4 q1 = *(const float4*)(v1 + k);
    a1 += x4.x * q1.x + x4.y * q1.y + x4.z * q1.z + x4.w * q1.w;
    float4 q2 = *(const float4*)(v2 + k);
    a2 += x4.x * q2.x + x4.y * q2.y + x4.z * q2.z + x4.w * q2.w;
    float4 q3 = *(const float4*)(v3 + k);
    a3 += x4.x * q3.x + x4.y * q3.y + x4.z * q3.z + x4.w * q3.w;
  }
  if (kh == 1) {
    int tk = (t == 0) ? 0 : text[bb * Tsz + (t - 1)];
    a0 += Wih[(size_t)(0 * Hsz + j) * 1200 + 600 + tk];
    a1 += Wih[(size_t)(1 * Hsz + j) * 1200 + 600 + tk];
    a2 += Wih[(size_t)(2 * Hsz + j) * 1200 + 600 + tk];
    a3 += Wih[(size_t)(3 * Hsz + j) * 1200 + 600 + tk];
    G.part[bi][jl] = make_float4(a0, a1, a2, a3);
  }
  __syncthreads();
  if (kh == 0) {
    float4 p = G.part[bi][jl];
    a0 += p.x + bih[j] + bhh[j];
    a1 += p.y + bih[512 + j] + bhh[512 + j];
    a2 += p.z + bih[1024 + j] + bhh[1024 + j];
    a3 += p.w + bih[1536 + j] + bhh[1536 + j];
    float ig = 1.f / (1.f + __expf(-a0));
    float fg = 1.f / (1.f + __expf(-a1));
    float gg = fast_tanh(a2);
    float og = 1.f / (1.f + __expf(-a3));
    float c = fg * cin[bb * Hsz + j] + ig * gg;
    float hN = og * fast_tanh(c);
    cout[bb * Hsz + j] = c;
    hnextf[bb * Hsz + j] = hN;
    hnext16[(size_t)bb * Hsz + j] = __float2half(hN);
  }
}

// ---------------- probs = softmax(hid16 @ W_gen^T + b_gen) ----------------
__global__ __launch_bounds__(256) void k_gen(const __half* __restrict__ hid16,
                                             const float* __restrict__ Wg,
                                             const float* __restrict__ bg,
                                             float* __restrict__ out) {
  __shared__ __align__(16) float sm[16 * 600];
  int m0 = blockIdx.x * 16;
  for (int idx = threadIdx.x; idx < 16 * 64; idx += 256) {
    int r = idx >> 6, k8 = (idx & 63) * 8;
    int m = m0 + r;
    int bb = m / Tsz, tt = m - bb * Tsz;
    float4 raw = *(const float4*)&hid16[((size_t)tt * Bsz + bb) * Hsz + k8];
    const __half2* h2p = (const __half2*)&raw;
    float2 f0 = __half22float2(h2p[0]);
    float2 f1 = __half22float2(h2p[1]);
    float2 f2 = __half22float2(h2p[2]);
    float2 f3 = __half22float2(h2p[3]);
    float* d = &sm[r * 520 + k8];
    d[0] = f0.x; d[1] = f0.y; d[2] = f1.x; d[3] = f1.y;
    d[4] = f2.x; d[5] = f2.y; d[6] = f3.x; d[7] = f3.y;
  }
  __syncthreads();
  int rg = threadIdx.x & 3, cg = threadIdx.x >> 2;
  int r0 = rg * 4;
  bool has2 = (cg < 22);
  float acc[12][4] = {};
  for (int k = 0; k < 512; k += 4) {
    float4 a[4];
#pragma unroll
    for (int i = 0; i < 4; ++i) a[i] = *(const float4*)&sm[(r0 + i) * 520 + k];
#pragma unroll
    for (int p = 0; p < 3; ++p) {
      if (p == 2 && !has2) continue;
#pragma unroll
      for (int i = 0; i < 4; ++i) {
        int c = p * 256 + cg * 4 + i;
        float4 w = *(const float4*)&Wg[(size_t)c * Hsz + k];
        int ci = p * 4 + i;
#pragma unroll
        for (int r = 0; r < 4; ++r)
          acc[ci][r] += a[r].x * w.x + a[r].y * w.y + a[r].z * w.z + a[r].w * w.w;
      }
    }
  }
  __syncthreads();
#pragma unroll
  for (int p = 0; p < 3; ++p) {
    if (p == 2 && !has2) continue;
#pragma unroll
    for (int i = 0; i < 4; ++i) {
      int c = p * 256 + cg * 4 + i;
      float bgc = bg[c];
#pragma unroll
      for (int r = 0; r < 4; ++r) sm[(r0 + r) * 600 + c] = acc[p * 4 + i][r] + bgc;
    }
  }
  __syncthreads();
  int wv = threadIdx.x >> 6, ln = threadIdx.x & 63;
  for (int r = wv; r < 16; r += 4) {
    float* row = sm + r * 600;
    float mx = -1e30f;
    for (int c = ln; c < 600; c += 64) mx = fmaxf(mx, row[c]);
#pragma unroll
    for (int off = 32; off > 0; off >>= 1) mx = fmaxf(mx, __shfl_xor(mx, off));
    float ssum = 0.f;
    for (int c = ln; c < 600; c += 64) {
      float ex = __expf(row[c] - mx);
      row[c] = ex;
      ssum += ex;
    }
#pragma unroll
    for (int off = 32; off > 0; off >>= 1) ssum += __shfl_xor(ssum, off);
    float inv = __fdividef(1.f, ssum);
    float* op = out + (size_t)(m0 + r) * 600;
    for (int c = ln; c < 600; c += 64) op[c] = row[c] * inv;
  }
}

extern "C" void kernel_launch(void* const* d_in, const int* in_sizes, int n_in,
                              void* d_out, int out_size, void* d_ws, size_t ws_size,
                              hipStream_t stream) {
  const float* bH = (const float*)d_in[0];
  const int* text = (const int*)d_in[1];  // harness converts int64 -> int32
  const float* Wi2h = (const float*)d_in[2];
  const float* Wh2h = (const float*)d_in[3];
  const float* bh2h = (const float*)d_in[4];
  const float* Wsc = (const float*)d_in[5];
  const float* Wih = (const float*)d_in[6];
  const float* Whh = (const float*)d_in[7];
  const float* bih = (const float*)d_in[8];
  const float* bhh = (const float*)d_in[9];
  const float* Wg = (const float*)d_in[10];
  const float* bg = (const float*)d_in[11];
  float* out = (float*)d_out;

  char* ws = (char*)d_ws;
  size_t off = 0;
  __half* Hp16 = (__half*)(ws + off);  off += (size_t)Bsz * Ssz * Hsz * 2;   // 67.1 MB
  __half* bH16T = (__half*)(ws + off); off += (size_t)Bsz * Vsz * Ssz * 2;   // 78.6 MB
  __half* hid16 = (__half*)(ws + off); off += (size_t)Tsz * Bsz * Hsz * 2;   // 15.9 MB
  float* h_pp = (float*)(ws + off);    off += (size_t)2 * Bsz * Hsz * 4;     // 0.5 MB
  float* cb = (float*)(ws + off);      off += (size_t)2 * Bsz * Hsz * 4;     // 0.5 MB
  float* ctx = (float*)(ws + off);     off += (size_t)Bsz * Vsz * 4;         // 0.3 MB

  hipMemsetAsync(h_pp, 0, (size_t)2 * Bsz * Hsz * 4, stream);
  hipMemsetAsync(cb, 0, (size_t)2 * Bsz * Hsz * 4, stream);

  k_hp<<<(Bsz * Ssz) / 16, 256, 0, stream>>>(bH, Wi2h, Hp16, bH16T);

  for (int t = 0; t < Tsz; ++t) {
    const float* hprev = h_pp + (size_t)(t & 1) * Bsz * Hsz;
    float* hnextf = h_pp + (size_t)((t + 1) & 1) * Bsz * Hsz;
    const float* cin = cb + (size_t)(t & 1) * Bsz * Hsz;
    float* cout = cb + (size_t)((t + 1) & 1) * Bsz * Hsz;
    k_att<<<Bsz, 512, 0, stream>>>(bH16T, Hp16, Wh2h, bh2h, Wsc, hprev, ctx);
    k_gates<<<512, 256, 0, stream>>>(ctx, hprev, Wih, Whh, bih, bhh, text, t,
                                     cin, cout, hnextf,
                                     hid16 + (size_t)t * Bsz * Hsz);
  }

  k_gen<<<(Bsz * Tsz) / 16, 256, 0, stream>>>(hid16, Wg, bg, out);
}

// Round 7
// 32435.022 us; speedup vs baseline: 3.6106x; 1.0329x over previous
//
#include <hip/hip_runtime.h>
#include <hip/hip_fp16.h>
#include <stdint.h>

#define Bsz 128
#define Ssz 512
#define Vsz 600
#define Hsz 512
#define Tsz 121

// branch-free 6-op tanh: tanh(x) = 1 - 2/(1 + e^{2x}); exact at +/-inf, ~1e-6 abs err
__device__ __forceinline__ float fast_tanh(float x) {
  float e = __expf(x + x);
  return 1.0f - __fdividef(2.0f, 1.0f + e);
}

// ---------------- one-time: WiT[k][c] = Wi[c][k]  (600x512 transpose) ----------------
__global__ __launch_bounds__(256) void k_wt(const float* __restrict__ Wi,
                                            float* __restrict__ WiT) {
  __shared__ float T[32][25];
  int k0 = blockIdx.x * 24, c0 = blockIdx.y * 32;
  for (int idx = threadIdx.x; idx < 32 * 24; idx += 256) {
    int i = idx / 24, j = idx - i * 24;
    T[i][j] = Wi[(size_t)(c0 + i) * 600 + k0 + j];
  }
  __syncthreads();
  for (int idx = threadIdx.x; idx < 24 * 32; idx += 256) {
    int j = idx >> 5, i = idx & 31;
    WiT[(size_t)(k0 + j) * 512 + c0 + i] = T[i][j];
  }
}

// ---- one-time: Hp16 = (batch_H @ W_i2h^T) fp16 [b][s][k], bH16 = batch_H fp16 [b][s][v] ----
__global__ __launch_bounds__(256) void k_hp(const float* __restrict__ bH,
                                            const float* __restrict__ WiT,
                                            __half* __restrict__ Hp,
                                            __half* __restrict__ bH16) {
  __shared__ __align__(16) float As[16][604];
  int m0 = blockIdx.x * 16;
  for (int idx = threadIdx.x; idx < 16 * 600; idx += 256) {
    int r = idx / 600, k = idx - r * 600;
    As[r][k] = bH[(size_t)(m0 + r) * 600 + k];
  }
  __syncthreads();
  // straight fp16 cast of the staged tile
  for (int idx = threadIdx.x; idx < 16 * 300; idx += 256) {
    int r = idx / 300, v2 = (idx - r * 300) * 2;
    __half2 h = __floats2half2_rn(As[r][v2], As[r][v2 + 1]);
    *(__half2*)&bH16[(size_t)(m0 + r) * 600 + v2] = h;
  }
  int rg = threadIdx.x & 3, cg = threadIdx.x >> 2;
  int r0 = rg * 4;
  for (int pass = 0; pass < 2; ++pass) {
    int c0 = pass * 256 + cg * 4;
    float acc[4][4] = {};
    for (int k = 0; k < 600; k += 4) {
      float4 w0 = *(const float4*)&WiT[(size_t)(k + 0) * 512 + c0];
      float4 w1 = *(const float4*)&WiT[(size_t)(k + 1) * 512 + c0];
      float4 w2 = *(const float4*)&WiT[(size_t)(k + 2) * 512 + c0];
      float4 w3 = *(const float4*)&WiT[(size_t)(k + 3) * 512 + c0];
#pragma unroll
      for (int i = 0; i < 4; ++i) {
        float4 a = *(const float4*)&As[r0 + i][k];
        acc[i][0] += a.x * w0.x + a.y * w1.x + a.z * w2.x + a.w * w3.x;
        acc[i][1] += a.x * w0.y + a.y * w1.y + a.z * w2.y + a.w * w3.y;
        acc[i][2] += a.x * w0.z + a.y * w1.z + a.z * w2.z + a.w * w3.z;
        acc[i][3] += a.x * w0.w + a.y * w1.w + a.z * w2.w + a.w * w3.w;
      }
    }
#pragma unroll
    for (int i = 0; i < 4; ++i) {
      __half2 p01 = __floats2half2_rn(acc[i][0], acc[i][1]);
      __half2 p23 = __floats2half2_rn(acc[i][2], acc[i][3]);
      union { __half2 h2[2]; float2 f2; } u;
      u.h2[0] = p01; u.h2[1] = p23;
      *(float2*)&Hp[(size_t)(m0 + r0 + i) * Hsz + c0] = u.f2;
    }
  }
}

// ---------------- pp = h_prev @ W_h2h^T + b_h2h ----------------
// grid dim3(Bsz, 4): (batch, j-quad of 128); 256 thr = 128 j-lanes x 2 k-halves
__global__ __launch_bounds__(256) void k_pp(const float* __restrict__ hprev,
                                            const float* __restrict__ W,
                                            const float* __restrict__ bias,
                                            float* __restrict__ pp) {
  __shared__ __align__(16) float hs[512];
  __shared__ float part[128];
  int b = blockIdx.x, jq = blockIdx.y;
  int tid = threadIdx.x;
  hs[tid] = hprev[b * Hsz + tid];
  hs[tid + 256] = hprev[b * Hsz + 256 + tid];
  __syncthreads();
  int jl = tid & 127, kh = tid >> 7;
  int j = jq * 128 + jl;
  const float* wrow = W + (size_t)j * Hsz + kh * 256;
  const float* hp = hs + kh * 256;
  float acc = 0.f;
#pragma unroll 4
  for (int k = 0; k < 256; k += 4) {
    float4 w = *(const float4*)(wrow + k);
    float4 h4 = *(const float4*)(hp + k);
    acc += w.x * h4.x + w.y * h4.y + w.z * h4.z + w.w * h4.w;
  }
  if (kh == 1) part[jl] = acc;
  __syncthreads();
  if (kh == 0) pp[b * Hsz + j] = acc + part[jl] + bias[j];
}

// ---------------- e[b,s] = Wsc . tanh(Hp[b,s,:] + pp[b,:]) ----------------
// 512 blocks (b x 4 s-tiles of 128), 256 thr = 4 waves; wave owns s, lane owns 8 k
__global__ __launch_bounds__(256) void k_e(const __half* __restrict__ Hp,
                                           const float* __restrict__ pp,
                                           const float* __restrict__ Wsc,
                                           float* __restrict__ ev) {
  __shared__ __align__(16) float pps[512];
  __shared__ __align__(16) float wss[512];
  int b = blockIdx.x >> 2, tile = blockIdx.x & 3;
  int tid = threadIdx.x;
  for (int i = tid; i < 512; i += 256) {
    pps[i] = pp[b * Hsz + i];
    wss[i] = Wsc[i];
  }
  __syncthreads();
  int wv = tid >> 6, ln = tid & 63;
  float p8[8], w8[8];
  {
    float4 pa = *(const float4*)&pps[ln * 8];
    float4 pb = *(const float4*)&pps[ln * 8 + 4];
    float4 wa = *(const float4*)&wss[ln * 8];
    float4 wb = *(const float4*)&wss[ln * 8 + 4];
    p8[0] = pa.x; p8[1] = pa.y; p8[2] = pa.z; p8[3] = pa.w;
    p8[4] = pb.x; p8[5] = pb.y; p8[6] = pb.z; p8[7] = pb.w;
    w8[0] = wa.x; w8[1] = wa.y; w8[2] = wa.z; w8[3] = wa.w;
    w8[4] = wb.x; w8[5] = wb.y; w8[6] = wb.z; w8[7] = wb.w;
  }
  int sbase = tile * 128 + wv * 32;
  const __half* hbase = Hp + ((size_t)b * Ssz + sbase) * Hsz + ln * 8;
#pragma unroll 2
  for (int it = 0; it < 32; ++it) {
    float4 raw = *(const float4*)(hbase + (size_t)it * Hsz);
    const __half2* h2p = (const __half2*)&raw;
    float2 f0 = __half22float2(h2p[0]);
    float2 f1 = __half22float2(h2p[1]);
    float2 f2 = __half22float2(h2p[2]);
    float2 f3 = __half22float2(h2p[3]);
    float acc = w8[0] * fast_tanh(f0.x + p8[0]);
    acc += w8[1] * fast_tanh(f0.y + p8[1]);
    acc += w8[2] * fast_tanh(f1.x + p8[2]);
    acc += w8[3] * fast_tanh(f1.y + p8[3]);
    acc += w8[4] * fast_tanh(f2.x + p8[4]);
    acc += w8[5] * fast_tanh(f2.y + p8[5]);
    acc += w8[6] * fast_tanh(f3.x + p8[6]);
    acc += w8[7] * fast_tanh(f3.y + p8[7]);
#pragma unroll
    for (int off = 32; off > 0; off >>= 1) acc += __shfl_xor(acc, off);
    if (ln == 0) ev[b * Ssz + sbase + it] = acc;
  }
}

// ---------------- softmax(e) then ctx = alpha @ bH16 ----------------
// 512 blocks (b x 4 v-chunks of 150), 256 thr = 4 waves (s-groups of 128)
__global__ __launch_bounds__(256) void k_ctx(const __half* __restrict__ bH16,
                                             const float* __restrict__ ev,
                                             float* __restrict__ ctx) {
  __shared__ __align__(16) float al[512];
  __shared__ float red[8];
  __shared__ float part[3][152];
  int b = blockIdx.x >> 2, vq = blockIdx.x & 3;
  int tid = threadIdx.x;
  int wv = tid >> 6, ln = tid & 63;
  float e0 = ev[b * Ssz + tid], e1 = ev[b * Ssz + 256 + tid];
  float m = fmaxf(e0, e1);
#pragma unroll
  for (int off = 32; off > 0; off >>= 1) m = fmaxf(m, __shfl_xor(m, off));
  if (ln == 0) red[wv] = m;
  __syncthreads();
  m = fmaxf(fmaxf(red[0], red[1]), fmaxf(red[2], red[3]));
  float x0 = __expf(e0 - m), x1 = __expf(e1 - m);
  float sum = x0 + x1;
#pragma unroll
  for (int off = 32; off > 0; off >>= 1) sum += __shfl_xor(sum, off);
  if (ln == 0) red[4 + wv] = sum;
  __syncthreads();
  sum = (red[4] + red[5]) + (red[6] + red[7]);
  float inv = __fdividef(1.f, sum);
  al[tid] = x0 * inv;
  al[tid + 256] = x1 * inv;
  __syncthreads();

  int v0 = vq * 150;
  const __half* base = bH16 + ((size_t)b * Ssz + (size_t)wv * 128) * Vsz + v0;
  const float* ap = al + wv * 128;
  float a0x = 0.f, a0y = 0.f, a1x = 0.f, a1y = 0.f;
  bool g = (ln < 11);
#pragma unroll 4
  for (int s2 = 0; s2 < 128; ++s2) {
    float a = ap[s2];
    const __half* row = base + (size_t)s2 * Vsz;
    float2 f = __half22float2(*(const __half2*)&row[2 * ln]);
    a0x += a * f.x;
    a0y += a * f.y;
    if (g) {
      float2 f2 = __half22float2(*(const __half2*)&row[128 + 2 * ln]);
      a1x += a * f2.x;
      a1y += a * f2.y;
    }
  }
  if (wv > 0) {
    part[wv - 1][2 * ln] = a0x;
    part[wv - 1][2 * ln + 1] = a0y;
    if (g) {
      part[wv - 1][128 + 2 * ln] = a1x;
      part[wv - 1][129 + 2 * ln] = a1y;
    }
  }
  __syncthreads();
  if (wv == 0) {
    a0x += part[0][2 * ln] + part[1][2 * ln] + part[2][2 * ln];
    a0y += part[0][2 * ln + 1] + part[1][2 * ln + 1] + part[2][2 * ln + 1];
    float2 o = make_float2(a0x, a0y);
    *(float2*)&ctx[b * Vsz + v0 + 2 * ln] = o;
    if (g) {
      a1x += part[0][128 + 2 * ln] + part[1][128 + 2 * ln] + part[2][128 + 2 * ln];
      a1y += part[0][129 + 2 * ln] + part[1][129 + 2 * ln] + part[2][129 + 2 * ln];
      float2 o2 = make_float2(a1x, a1y);
      *(float2*)&ctx[b * Vsz + v0 + 128 + 2 * ln] = o2;
    }
  }
}

// ---------------- gates + LSTM pointwise ----------------
// 512 blocks x 256 thr: bt = 4 b's, jt = 32 j's (XCD-grouped), kh split x2
struct ShG { float xs[4][1112]; float4 part[4][32]; };

__global__ __launch_bounds__(256) void k_gates(
    const float* __restrict__ ctx, const float* __restrict__ hprev,
    const float* __restrict__ Wih, const float* __restrict__ Whh,
    const float* __restrict__ bih, const float* __restrict__ bhh,
    const int* __restrict__ text, int t,
    const float* __restrict__ cin, float* __restrict__ cout,
    float* __restrict__ hnextf, __half* __restrict__ hnext16) {
  __shared__ __align__(16) ShG G;
  const int bid = blockIdx.x, tid = threadIdx.x;
  const int jt = (bid & 7) * 2 + ((bid >> 3) & 1);  // XCD d%8 owns 2 j-tiles
  const int bt = bid >> 4;
  int b0 = bt * 4, j0 = jt * 32;
  for (int idx = tid; idx < 4 * 600; idx += 256) {
    int r = idx / 600, k = idx - r * 600;
    G.xs[r][k] = ctx[(b0 + r) * Vsz + k];
  }
  for (int idx = tid; idx < 4 * 512; idx += 256) {
    int r = idx >> 9, k = idx & 511;
    G.xs[r][600 + k] = hprev[(b0 + r) * Hsz + k];
  }
  __syncthreads();
  int bi = tid >> 6, jl = tid & 31, kh = (tid >> 5) & 1;
  int bb = b0 + bi, j = j0 + jl;
  float a0 = 0.f, a1 = 0.f, a2 = 0.f, a3 = 0.f;
  const float* xr = G.xs[bi];
  const float* w0 = Wih + (size_t)(0 * Hsz + j) * 1200 + kh * 300;
  const float* w1 = Wih + (size_t)(1 * Hsz + j) * 1200 + kh * 300;
  const float* w2 = Wih + (size_t)(2 * Hsz + j) * 1200 + kh * 300;
  const float* w3 = Wih + (size_t)(3 * Hsz + j) * 1200 + kh * 300;
  const float* xc = xr + kh * 300;
#pragma unroll 2
  for (int k = 0; k < 300; k += 4) {
    float4 x4 = *(const float4*)(xc + k);
    float4 q0 = *(const float4*)(w0 + k);
    a0 += x4.x * q0.x + x4.y * q0.y + x4.z * q0.z + x4.w * q0.w;
    float4 q1 = *(const float4*)(w1 + k);
    a1 += x4.x * q1.x + x4.y * q1.y + x4.z * q1.z + x4.w * q1.w;
    float4 q2 = *(const float4*)(w2 + k);
    a2 += x4.x * q2.x + x4.y * q2.y + x4.z * q2.z + x4.w * q2.w;
    float4 q3 = *(const float4*)(w3 + k);
    a3 += x4.x * q3.x + x4.y * q3.y + x4.z * q3.z + x4.w * q3.w;
  }
  const float* v0 = Whh + (size_t)(0 * Hsz + j) * Hsz + kh * 256;
  const float* v1 = Whh + (size_t)(1 * Hsz + j) * Hsz + kh * 256;
  const float* v2 = Whh + (size_t)(2 * Hsz + j) * Hsz + kh * 256;
  const float* v3 = Whh + (size_t)(3 * Hsz + j) * Hsz + kh * 256;
  const float* xh = xr + 600 + kh * 256;
#pragma unroll 2
  for (int k = 0; k < 256; k += 4) {
    float4 x4 = *(const float4*)(xh + k);
    float4 q0 = *(const float4*)(v0 + k);
    a0 += x4.x * q0.x + x4.y * q0.y + x4.z * q0.z + x4.w * q0.w;
    float4 q1 = *(const float4*)(v1 + k);
    a1 += x4.x * q1.x + x4.y * q1.y + x4.z * q1.z + x4.w * q1.w;
    float4 q2 = *(const float4*)(v2 + k);
    a2 += x4.x * q2.x + x4.y * q2.y + x4.z * q2.z + x4.w * q2.w;
    float4 q3 = *(const float4*)(v3 + k);
    a3 += x4.x * q3.x + x4.y * q3.y + x4.z * q3.z + x4.w * q3.w;
  }
  if (kh == 1) {
    int tk = (t == 0) ? 0 : text[bb * Tsz + (t - 1)];
    a0 += Wih[(size_t)(0 * Hsz + j) * 1200 + 600 + tk];
    a1 += Wih[(size_t)(1 * Hsz + j) * 1200 + 600 + tk];
    a2 += Wih[(size_t)(2 * Hsz + j) * 1200 + 600 + tk];
    a3 += Wih[(size_t)(3 * Hsz + j) * 1200 + 600 + tk];
    G.part[bi][jl] = make_float4(a0, a1, a2, a3);
  }
  __syncthreads();
  if (kh == 0) {
    float4 p = G.part[bi][jl];
    a0 += p.x + bih[j] + bhh[j];
    a1 += p.y + bih[512 + j] + bhh[512 + j];
    a2 += p.z + bih[1024 + j] + bhh[1024 + j];
    a3 += p.w + bih[1536 + j] + bhh[1536 + j];
    float ig = 1.f / (1.f + __expf(-a0));
    float fg = 1.f / (1.f + __expf(-a1));
    float gg = fast_tanh(a2);
    float og = 1.f / (1.f + __expf(-a3));
    float c = fg * cin[bb * Hsz + j] + ig * gg;
    float hN = og * fast_tanh(c);
    cout[bb * Hsz + j] = c;
    hnextf[bb * Hsz + j] = hN;
    hnext16[(size_t)bb * Hsz + j] = __float2half(hN);
  }
}

// ---------------- probs = softmax(hid16 @ W_gen^T + b_gen) ----------------
__global__ __launch_bounds__(256) void k_gen(const __half* __restrict__ hid16,
                                             const float* __restrict__ Wg,
                                             const float* __restrict__ bg,
                                             float* __restrict__ out) {
  __shared__ __align__(16) float sm[16 * 600];
  int m0 = blockIdx.x * 16;
  for (int idx = threadIdx.x; idx < 16 * 64; idx += 256) {
    int r = idx >> 6, k8 = (idx & 63) * 8;
    int m = m0 + r;
    int bb = m / Tsz, tt = m - bb * Tsz;
    float4 raw = *(const float4*)&hid16[((size_t)tt * Bsz + bb) * Hsz + k8];
    const __half2* h2p = (const __half2*)&raw;
    float2 f0 = __half22float2(h2p[0]);
    float2 f1 = __half22float2(h2p[1]);
    float2 f2 = __half22float2(h2p[2]);
    float2 f3 = __half22float2(h2p[3]);
    float* d = &sm[r * 520 + k8];
    d[0] = f0.x; d[1] = f0.y; d[2] = f1.x; d[3] = f1.y;
    d[4] = f2.x; d[5] = f2.y; d[6] = f3.x; d[7] = f3.y;
  }
  __syncthreads();
  int rg = threadIdx.x & 3, cg = threadIdx.x >> 2;
  int r0 = rg * 4;
  bool has2 = (cg < 22);
  float acc[12][4] = {};
  for (int k = 0; k < 512; k += 4) {
    float4 a[4];
#pragma unroll
    for (int i = 0; i < 4; ++i) a[i] = *(const float4*)&sm[(r0 + i) * 520 + k];
#pragma unroll
    for (int p = 0; p < 3; ++p) {
      if (p == 2 && !has2) continue;
#pragma unroll
      for (int i = 0; i < 4; ++i) {
        int c = p * 256 + cg * 4 + i;
        float4 w = *(const float4*)&Wg[(size_t)c * Hsz + k];
        int ci = p * 4 + i;
#pragma unroll
        for (int r = 0; r < 4; ++r)
          acc[ci][r] += a[r].x * w.x + a[r].y * w.y + a[r].z * w.z + a[r].w * w.w;
      }
    }
  }
  __syncthreads();
#pragma unroll
  for (int p = 0; p < 3; ++p) {
    if (p == 2 && !has2) continue;
#pragma unroll
    for (int i = 0; i < 4; ++i) {
      int c = p * 256 + cg * 4 + i;
      float bgc = bg[c];
#pragma unroll
      for (int r = 0; r < 4; ++r) sm[(r0 + r) * 600 + c] = acc[p * 4 + i][r] + bgc;
    }
  }
  __syncthreads();
  int wv = threadIdx.x >> 6, ln = threadIdx.x & 63;
  for (int r = wv; r < 16; r += 4) {
    float* row = sm + r * 600;
    float mx = -1e30f;
    for (int c = ln; c < 600; c += 64) mx = fmaxf(mx, row[c]);
#pragma unroll
    for (int off = 32; off > 0; off >>= 1) mx = fmaxf(mx, __shfl_xor(mx, off));
    float ssum = 0.f;
    for (int c = ln; c < 600; c += 64) {
      float ex = __expf(row[c] - mx);
      row[c] = ex;
      ssum += ex;
    }
#pragma unroll
    for (int off = 32; off > 0; off >>= 1) ssum += __shfl_xor(ssum, off);
    float inv = __fdividef(1.f, ssum);
    float* op = out + (size_t)(m0 + r) * 600;
    for (int c = ln; c < 600; c += 64) op[c] = row[c] * inv;
  }
}

extern "C" void kernel_launch(void* const* d_in, const int* in_sizes, int n_in,
                              void* d_out, int out_size, void* d_ws, size_t ws_size,
                              hipStream_t stream) {
  const float* bH = (const float*)d_in[0];
  const int* text = (const int*)d_in[1];  // harness converts int64 -> int32
  const float* Wi2h = (const float*)d_in[2];
  const float* Wh2h = (const float*)d_in[3];
  const float* bh2h = (const float*)d_in[4];
  const float* Wsc = (const float*)d_in[5];
  const float* Wih = (const float*)d_in[6];
  const float* Whh = (const float*)d_in[7];
  const float* bih = (const float*)d_in[8];
  const float* bhh = (const float*)d_in[9];
  const float* Wg = (const float*)d_in[10];
  const float* bg = (const float*)d_in[11];
  float* out = (float*)d_out;

  char* ws = (char*)d_ws;
  size_t off = 0;
  __half* Hp16 = (__half*)(ws + off);  off += (size_t)Bsz * Ssz * Hsz * 2;   // 67.1 MB
  __half* bH16 = (__half*)(ws + off);  off += (size_t)Bsz * Ssz * Vsz * 2;   // 78.6 MB
  __half* hid16 = (__half*)(ws + off); off += (size_t)Tsz * Bsz * Hsz * 2;   // 15.9 MB
  float* WiT = (float*)(ws + off);     off += (size_t)600 * 512 * 4;         // 1.2 MB
  float* h_pp = (float*)(ws + off);    off += (size_t)2 * Bsz * Hsz * 4;     // 0.5 MB
  float* cb = (float*)(ws + off);      off += (size_t)2 * Bsz * Hsz * 4;     // 0.5 MB
  float* pp = (float*)(ws + off);      off += (size_t)Bsz * Hsz * 4;         // 0.25 MB
  float* ev = (float*)(ws + off);      off += (size_t)Bsz * Ssz * 4;         // 0.25 MB
  float* ctx = (float*)(ws + off);     off += (size_t)Bsz * Vsz * 4;         // 0.3 MB

  hipMemsetAsync(h_pp, 0, (size_t)2 * Bsz * Hsz * 4, stream);
  hipMemsetAsync(cb, 0, (size_t)2 * Bsz * Hsz * 4, stream);

  k_wt<<<dim3(25, 16), 256, 0, stream>>>(Wi2h, WiT);
  k_hp<<<(Bsz * Ssz) / 16, 256, 0, stream>>>(bH, WiT, Hp16, bH16);

  for (int t = 0; t < Tsz; ++t) {
    const float* hprev = h_pp + (size_t)(t & 1) * Bsz * Hsz;
    float* hnextf = h_pp + (size_t)((t + 1) & 1) * Bsz * Hsz;
    const float* cin = cb + (size_t)(t & 1) * Bsz * Hsz;
    float* cout = cb + (size_t)((t + 1) & 1) * Bsz * Hsz;
    k_pp<<<dim3(Bsz, 4), 256, 0, stream>>>(hprev, Wh2h, bh2h, pp);
    k_e<<<Bsz * 4, 256, 0, stream>>>(Hp16, pp, Wsc, ev);
    k_ctx<<<Bsz * 4, 256, 0, stream>>>(bH16, ev, ctx);
    k_gates<<<512, 256, 0, stream>>>(ctx, hprev, Wih, Whh, bih, bhh, text, t,
                                     cin, cout, hnextf,
                                     hid16 + (size_t)t * Bsz * Hsz);
  }

  k_gen<<<(Bsz * Tsz) / 16, 256, 0, stream>>>(hid16, Wg, bg, out);
}

// Round 8
// 29142.804 us; speedup vs baseline: 4.0185x; 1.1130x over previous
//
#include <hip/hip_runtime.h>
#include <hip/hip_fp16.h>
#include <stdint.h>

#define Bsz 128
#define Ssz 512
#define Vsz 600
#define Hsz 512
#define Tsz 121
#define NBLK 512
#define FSTR 32  // flag stride in u32 (128 B per flag line)

// branch-free 6-op tanh: tanh(x) = 1 - 2/(1 + e^{2x}); exact at +/-inf, ~1e-6 abs err
__device__ __forceinline__ float fast_tanh(float x) {
  float e = __expf(x + x);
  return 1.0f - __fdividef(2.0f, 1.0f + e);
}

// ---------------- one-time: WiT[k][c] = Wi[c][k]  (600x512 transpose) ----------------
__global__ __launch_bounds__(256) void k_wt(const float* __restrict__ Wi,
                                            float* __restrict__ WiT) {
  __shared__ float T[32][25];
  int k0 = blockIdx.x * 24, c0 = blockIdx.y * 32;
  for (int idx = threadIdx.x; idx < 32 * 24; idx += 256) {
    int i = idx / 24, j = idx - i * 24;
    T[i][j] = Wi[(size_t)(c0 + i) * 600 + k0 + j];
  }
  __syncthreads();
  for (int idx = threadIdx.x; idx < 24 * 32; idx += 256) {
    int j = idx >> 5, i = idx & 31;
    WiT[(size_t)(k0 + j) * 512 + c0 + i] = T[i][j];
  }
}

// ---- one-time: Hp16 = (batch_H @ W_i2h^T) fp16 [b][s][k], bH16 = batch_H fp16 [b][s][v] ----
__global__ __launch_bounds__(256) void k_hp(const float* __restrict__ bH,
                                            const float* __restrict__ WiT,
                                            __half* __restrict__ Hp,
                                            __half* __restrict__ bH16) {
  __shared__ __align__(16) float As[16][604];
  int m0 = blockIdx.x * 16;
  for (int idx = threadIdx.x; idx < 16 * 600; idx += 256) {
    int r = idx / 600, k = idx - r * 600;
    As[r][k] = bH[(size_t)(m0 + r) * 600 + k];
  }
  __syncthreads();
  for (int idx = threadIdx.x; idx < 16 * 300; idx += 256) {
    int r = idx / 300, v2 = (idx - r * 300) * 2;
    __half2 h = __floats2half2_rn(As[r][v2], As[r][v2 + 1]);
    *(__half2*)&bH16[(size_t)(m0 + r) * 600 + v2] = h;
  }
  int rg = threadIdx.x & 3, cg = threadIdx.x >> 2;
  int r0 = rg * 4;
  for (int pass = 0; pass < 2; ++pass) {
    int c0 = pass * 256 + cg * 4;
    float acc[4][4] = {};
    for (int k = 0; k < 600; k += 4) {
      float4 w0 = *(const float4*)&WiT[(size_t)(k + 0) * 512 + c0];
      float4 w1 = *(const float4*)&WiT[(size_t)(k + 1) * 512 + c0];
      float4 w2 = *(const float4*)&WiT[(size_t)(k + 2) * 512 + c0];
      float4 w3 = *(const float4*)&WiT[(size_t)(k + 3) * 512 + c0];
#pragma unroll
      for (int i = 0; i < 4; ++i) {
        float4 a = *(const float4*)&As[r0 + i][k];
        acc[i][0] += a.x * w0.x + a.y * w1.x + a.z * w2.x + a.w * w3.x;
        acc[i][1] += a.x * w0.y + a.y * w1.y + a.z * w2.y + a.w * w3.y;
        acc[i][2] += a.x * w0.z + a.y * w1.z + a.z * w2.z + a.w * w3.z;
        acc[i][3] += a.x * w0.w + a.y * w1.w + a.z * w2.w + a.w * w3.w;
      }
    }
#pragma unroll
    for (int i = 0; i < 4; ++i) {
      __half2 p01 = __floats2half2_rn(acc[i][0], acc[i][1]);
      __half2 p23 = __floats2half2_rn(acc[i][2], acc[i][3]);
      union { __half2 h2[2]; float2 f2; } u;
      u.h2[0] = p01; u.h2[1] = p23;
      *(float2*)&Hp[(size_t)(m0 + r0 + i) * Hsz + c0] = u.f2;
    }
  }
}

// ---------------- persistent step loop, relaxed-atomic flag sync ----------------
struct ShPP { float hs[512]; float part[128]; };
struct ShE  { float pps[512]; float wss[512]; };
struct ShC  { float al[512]; float red[8]; float part[3][152]; };
struct ShG  { float xs[4][1112]; float4 part[4][32]; };
union ShU { ShPP pp; ShE e; ShC c; ShG g; };

__device__ __forceinline__ unsigned ldf(const unsigned* f) {
  return __hip_atomic_load(f, __ATOMIC_RELAXED, __HIP_MEMORY_SCOPE_AGENT);
}
__device__ __forceinline__ void flag_wait(unsigned* f, unsigned tgt) {
  if (threadIdx.x == 0) {
    while (ldf(f) < tgt) __builtin_amdgcn_s_sleep(8);
  }
  __syncthreads();
}
__device__ __forceinline__ void flag_bump(unsigned* f) {
  __syncthreads();  // drains vmcnt(0): all data stores device-visible (sc1)
  if (threadIdx.x == 0)
    __hip_atomic_fetch_add(f, 1u, __ATOMIC_RELAXED, __HIP_MEMORY_SCOPE_AGENT);
}
__device__ __forceinline__ float ldg1(const float* p) {
  return __hip_atomic_load(p, __ATOMIC_RELAXED, __HIP_MEMORY_SCOPE_AGENT);
}
__device__ __forceinline__ void stg1(float* p, float v) {
  __hip_atomic_store(p, v, __ATOMIC_RELAXED, __HIP_MEMORY_SCOPE_AGENT);
}

__global__ __launch_bounds__(256, 2) void k_step(
    const __half* __restrict__ bH16, const __half* __restrict__ Hp,
    const float* __restrict__ Wh2h, const float* __restrict__ bh2h,
    const float* __restrict__ Wsc,
    const float* __restrict__ Wih, const float* __restrict__ Whh,
    const float* __restrict__ bih, const float* __restrict__ bhh,
    const int* __restrict__ text,
    float* __restrict__ h_pp, __half* __restrict__ hid16,
    float* __restrict__ pp, float* __restrict__ ev, float* __restrict__ ctx,
    unsigned* __restrict__ flags) {
  __shared__ __align__(16) ShU sh;
  const int bid = blockIdx.x, tid = threadIdx.x;
  unsigned* ppf = flags;
  unsigned* evf = flags + 128 * FSTR;
  unsigned* ctf = flags + 256 * FSTR;
  unsigned* hf  = flags + 384 * FSTR;
  const int b = bid >> 2, q = bid & 3;             // P/E/C roles
  const int bt = bid >> 4;                          // G role: 4 b's
  const int jt = (bid & 7) * 2 + ((bid >> 3) & 1);  // XCD-grouped j-tile
  float c_reg = 0.f;  // LSTM cell state (kh==0 lanes of G)

  for (int t = 0; t < Tsz; ++t) {
    const float* hprevf = h_pp + (size_t)(t & 1) * Bsz * Hsz;
    float* hnextf = h_pp + (size_t)((t + 1) & 1) * Bsz * Hsz;

    // ---- P: pp[b, q*128..] = hprev[b] @ W_h2h^T + b_h2h ----
    {
      if (t == 0) {
        if (tid < 128) stg1(&pp[b * Hsz + q * 128 + tid], bh2h[q * 128 + tid]);
      } else {
        flag_wait(hf + (size_t)(b >> 2) * FSTR, 16u * (unsigned)t);
        ShPP& P = sh.pp;
        P.hs[tid] = ldg1(&hprevf[b * Hsz + tid]);
        P.hs[tid + 256] = ldg1(&hprevf[b * Hsz + 256 + tid]);
        __syncthreads();
        int jl = tid & 127, kh = tid >> 7;
        int j = q * 128 + jl;
        const float* wrow = Wh2h + (size_t)j * Hsz + kh * 256;
        const float* hp = P.hs + kh * 256;
        float acc = 0.f;
#pragma unroll 4
        for (int k = 0; k < 256; k += 4) {
          float4 w = *(const float4*)(wrow + k);
          float4 h4 = *(const float4*)(hp + k);
          acc += w.x * h4.x + w.y * h4.y + w.z * h4.z + w.w * h4.w;
        }
        if (kh == 1) P.part[jl] = acc;
        __syncthreads();
        if (kh == 0) stg1(&pp[b * Hsz + j], acc + P.part[jl] + bh2h[j]);
      }
      flag_bump(ppf + (size_t)b * FSTR);
    }

    // ---- E: e[b, q-tile of 128 s] ; wave owns s, lane owns 8 k ----
    {
      flag_wait(ppf + (size_t)b * FSTR, 4u * (unsigned)(t + 1));
      ShE& E = sh.e;
      for (int i = tid; i < 512; i += 256) {
        E.pps[i] = ldg1(&pp[b * Hsz + i]);
        E.wss[i] = Wsc[i];
      }
      __syncthreads();
      int wv = tid >> 6, ln = tid & 63;
      float p8[8], w8[8];
      {
        float4 pa = *(const float4*)&E.pps[ln * 8];
        float4 pb = *(const float4*)&E.pps[ln * 8 + 4];
        float4 wa = *(const float4*)&E.wss[ln * 8];
        float4 wb = *(const float4*)&E.wss[ln * 8 + 4];
        p8[0] = pa.x; p8[1] = pa.y; p8[2] = pa.z; p8[3] = pa.w;
        p8[4] = pb.x; p8[5] = pb.y; p8[6] = pb.z; p8[7] = pb.w;
        w8[0] = wa.x; w8[1] = wa.y; w8[2] = wa.z; w8[3] = wa.w;
        w8[4] = wb.x; w8[5] = wb.y; w8[6] = wb.z; w8[7] = wb.w;
      }
      int sbase = q * 128 + wv * 32;
      const __half* hbase = Hp + ((size_t)b * Ssz + sbase) * Hsz + ln * 8;
#pragma unroll 2
      for (int it = 0; it < 32; ++it) {
        float4 raw = *(const float4*)(hbase + (size_t)it * Hsz);
        const __half2* h2p = (const __half2*)&raw;
        float2 f0 = __half22float2(h2p[0]);
        float2 f1 = __half22float2(h2p[1]);
        float2 f2 = __half22float2(h2p[2]);
        float2 f3 = __half22float2(h2p[3]);
        float acc = w8[0] * fast_tanh(f0.x + p8[0]);
        acc += w8[1] * fast_tanh(f0.y + p8[1]);
        acc += w8[2] * fast_tanh(f1.x + p8[2]);
        acc += w8[3] * fast_tanh(f1.y + p8[3]);
        acc += w8[4] * fast_tanh(f2.x + p8[4]);
        acc += w8[5] * fast_tanh(f2.y + p8[5]);
        acc += w8[6] * fast_tanh(f3.x + p8[6]);
        acc += w8[7] * fast_tanh(f3.y + p8[7]);
#pragma unroll
        for (int off = 32; off > 0; off >>= 1) acc += __shfl_xor(acc, off);
        if (ln == 0) stg1(&ev[b * Ssz + sbase + it], acc);
      }
      flag_bump(evf + (size_t)b * FSTR);
    }

    // ---- C: softmax(e[b]) then ctx[b, q*150..] = alpha @ bH16 ----
    {
      flag_wait(evf + (size_t)b * FSTR, 4u * (unsigned)(t + 1));
      ShC& C = sh.c;
      int wv = tid >> 6, ln = tid & 63;
      float e0 = ldg1(&ev[b * Ssz + tid]), e1 = ldg1(&ev[b * Ssz + 256 + tid]);
      float m = fmaxf(e0, e1);
#pragma unroll
      for (int off = 32; off > 0; off >>= 1) m = fmaxf(m, __shfl_xor(m, off));
      if (ln == 0) C.red[wv] = m;
      __syncthreads();
      m = fmaxf(fmaxf(C.red[0], C.red[1]), fmaxf(C.red[2], C.red[3]));
      float x0 = __expf(e0 - m), x1 = __expf(e1 - m);
      float sum = x0 + x1;
#pragma unroll
      for (int off = 32; off > 0; off >>= 1) sum += __shfl_xor(sum, off);
      if (ln == 0) C.red[4 + wv] = sum;
      __syncthreads();
      sum = (C.red[4] + C.red[5]) + (C.red[6] + C.red[7]);
      float inv = __fdividef(1.f, sum);
      C.al[tid] = x0 * inv;
      C.al[tid + 256] = x1 * inv;
      __syncthreads();
      int v0 = q * 150;
      const __half* base = bH16 + ((size_t)b * Ssz + (size_t)wv * 128) * Vsz + v0;
      const float* ap = C.al + wv * 128;
      float a0x = 0.f, a0y = 0.f, a1x = 0.f, a1y = 0.f;
      bool g = (ln < 11);
#pragma unroll 4
      for (int s2 = 0; s2 < 128; ++s2) {
        float a = ap[s2];
        const __half* row = base + (size_t)s2 * Vsz;
        float2 f = __half22float2(*(const __half2*)&row[2 * ln]);
        a0x += a * f.x;
        a0y += a * f.y;
        if (g) {
          float2 f2 = __half22float2(*(const __half2*)&row[128 + 2 * ln]);
          a1x += a * f2.x;
          a1y += a * f2.y;
        }
      }
      if (wv > 0) {
        C.part[wv - 1][2 * ln] = a0x;
        C.part[wv - 1][2 * ln + 1] = a0y;
        if (g) {
          C.part[wv - 1][128 + 2 * ln] = a1x;
          C.part[wv - 1][129 + 2 * ln] = a1y;
        }
      }
      __syncthreads();
      if (wv == 0) {
        a0x += C.part[0][2 * ln] + C.part[1][2 * ln] + C.part[2][2 * ln];
        a0y += C.part[0][2 * ln + 1] + C.part[1][2 * ln + 1] + C.part[2][2 * ln + 1];
        stg1(&ctx[b * Vsz + v0 + 2 * ln], a0x);
        stg1(&ctx[b * Vsz + v0 + 2 * ln + 1], a0y);
        if (g) {
          a1x += C.part[0][128 + 2 * ln] + C.part[1][128 + 2 * ln] + C.part[2][128 + 2 * ln];
          a1y += C.part[0][129 + 2 * ln] + C.part[1][129 + 2 * ln] + C.part[2][129 + 2 * ln];
          stg1(&ctx[b * Vsz + v0 + 128 + 2 * ln], a1x);
          stg1(&ctx[b * Vsz + v0 + 129 + 2 * ln], a1y);
        }
      }
      flag_bump(ctf + (size_t)b * FSTR);
    }

    // ---- G: gates + LSTM pointwise for (bt: 4 b's) x (jt: 32 j's) ----
    {
      unsigned tgt = 4u * (unsigned)(t + 1);
      if (tid < 4) {
        unsigned* f = ctf + (size_t)(bt * 4 + tid) * FSTR;
        while (ldf(f) < tgt) __builtin_amdgcn_s_sleep(8);
      }
      __syncthreads();
      ShG& G = sh.g;
      int b0 = bt * 4, j0 = jt * 32;
      for (int idx = tid; idx < 4 * 600; idx += 256) {
        int r = idx / 600, k = idx - r * 600;
        G.xs[r][k] = ldg1(&ctx[(b0 + r) * Vsz + k]);
      }
      if (t == 0) {
        for (int idx = tid; idx < 4 * 512; idx += 256) {
          int r = idx >> 9, k = idx & 511;
          G.xs[r][600 + k] = 0.f;
        }
      } else {
        for (int idx = tid; idx < 4 * 512; idx += 256) {
          int r = idx >> 9, k = idx & 511;
          G.xs[r][600 + k] = ldg1(&hprevf[(b0 + r) * Hsz + k]);
        }
      }
      __syncthreads();
      int bi = tid >> 6, jl = tid & 31, kh = (tid >> 5) & 1;
      int bb = b0 + bi, j = j0 + jl;
      float a0 = 0.f, a1 = 0.f, a2 = 0.f, a3 = 0.f;
      const float* xr = G.xs[bi];
      const float* w0 = Wih + (size_t)(0 * Hsz + j) * 1200 + kh * 300;
      const float* w1 = Wih + (size_t)(1 * Hsz + j) * 1200 + kh * 300;
      const float* w2 = Wih + (size_t)(2 * Hsz + j) * 1200 + kh * 300;
      const float* w3 = Wih + (size_t)(3 * Hsz + j) * 1200 + kh * 300;
      const float* xc = xr + kh * 300;
#pragma unroll 2
      for (int k = 0; k < 300; k += 4) {
        float4 x4 = *(const float4*)(xc + k);
        float4 q0 = *(const float4*)(w0 + k);
        a0 += x4.x * q0.x + x4.y * q0.y + x4.z * q0.z + x4.w * q0.w;
        float4 q1 = *(const float4*)(w1 + k);
        a1 += x4.x * q1.x + x4.y * q1.y + x4.z * q1.z + x4.w * q1.w;
        float4 q2 = *(const float4*)(w2 + k);
        a2 += x4.x * q2.x + x4.y * q2.y + x4.z * q2.z + x4.w * q2.w;
        float4 q3 = *(const float4*)(w3 + k);
        a3 += x4.x * q3.x + x4.y * q3.y + x4.z * q3.z + x4.w * q3.w;
      }
      const float* v0 = Whh + (size_t)(0 * Hsz + j) * Hsz + kh * 256;
      const float* v1 = Whh + (size_t)(1 * Hsz + j) * Hsz + kh * 256;
      const float* v2 = Whh + (size_t)(2 * Hsz + j) * Hsz + kh * 256;
      const float* v3 = Whh + (size_t)(3 * Hsz + j) * Hsz + kh * 256;
      const float* xh = xr + 600 + kh * 256;
#pragma unroll 2
      for (int k = 0; k < 256; k += 4) {
        float4 x4 = *(const float4*)(xh + k);
        float4 q0 = *(const float4*)(v0 + k);
        a0 += x4.x * q0.x + x4.y * q0.y + x4.z * q0.z + x4.w * q0.w;
        float4 q1 = *(const float4*)(v1 + k);
        a1 += x4.x * q1.x + x4.y * q1.y + x4.z * q1.z + x4.w * q1.w;
        float4 q2 = *(const float4*)(v2 + k);
        a2 += x4.x * q2.x + x4.y * q2.y + x4.z * q2.z + x4.w * q2.w;
        float4 q3 = *(const float4*)(v3 + k);
        a3 += x4.x * q3.x + x4.y * q3.y + x4.z * q3.z + x4.w * q3.w;
      }
      if (kh == 1) {
        int tk = (t == 0) ? 0 : text[bb * Tsz + (t - 1)];
        a0 += Wih[(size_t)(0 * Hsz + j) * 1200 + 600 + tk];
        a1 += Wih[(size_t)(1 * Hsz + j) * 1200 + 600 + tk];
        a2 += Wih[(size_t)(2 * Hsz + j) * 1200 + 600 + tk];
        a3 += Wih[(size_t)(3 * Hsz + j) * 1200 + 600 + tk];
        G.part[bi][jl] = make_float4(a0, a1, a2, a3);
      }
      __syncthreads();
      if (kh == 0) {
        float4 p = G.part[bi][jl];
        a0 += p.x + bih[j] + bhh[j];
        a1 += p.y + bih[512 + j] + bhh[512 + j];
        a2 += p.z + bih[1024 + j] + bhh[1024 + j];
        a3 += p.w + bih[1536 + j] + bhh[1536 + j];
        float ig = 1.f / (1.f + __expf(-a0));
        float fg = 1.f / (1.f + __expf(-a1));
        float gg = fast_tanh(a2);
        float og = 1.f / (1.f + __expf(-a3));
        c_reg = fg * c_reg + ig * gg;
        float hN = og * fast_tanh(c_reg);
        stg1(&hnextf[bb * Hsz + j], hN);
        hid16[(size_t)t * Bsz * Hsz + (size_t)bb * Hsz + j] = __float2half(hN);
      }
      flag_bump(hf + (size_t)bt * FSTR);
    }
  }
}

// ---------------- probs = softmax(hid16 @ W_gen^T + b_gen) ----------------
__global__ __launch_bounds__(256) void k_gen(const __half* __restrict__ hid16,
                                             const float* __restrict__ Wg,
                                             const float* __restrict__ bg,
                                             float* __restrict__ out) {
  __shared__ __align__(16) float sm[16 * 600];
  int m0 = blockIdx.x * 16;
  for (int idx = threadIdx.x; idx < 16 * 64; idx += 256) {
    int r = idx >> 6, k8 = (idx & 63) * 8;
    int m = m0 + r;
    int bb = m / Tsz, tt = m - bb * Tsz;
    float4 raw = *(const float4*)&hid16[((size_t)tt * Bsz + bb) * Hsz + k8];
    const __half2* h2p = (const __half2*)&raw;
    float2 f0 = __half22float2(h2p[0]);
    float2 f1 = __half22float2(h2p[1]);
    float2 f2 = __half22float2(h2p[2]);
    float2 f3 = __half22float2(h2p[3]);
    float* d = &sm[r * 520 + k8];
    d[0] = f0.x; d[1] = f0.y; d[2] = f1.x; d[3] = f1.y;
    d[4] = f2.x; d[5] = f2.y; d[6] = f3.x; d[7] = f3.y;
  }
  __syncthreads();
  int rg = threadIdx.x & 3, cg = threadIdx.x >> 2;
  int r0 = rg * 4;
  bool has2 = (cg < 22);
  float acc[12][4] = {};
  for (int k = 0; k < 512; k += 4) {
    float4 a[4];
#pragma unroll
    for (int i = 0; i < 4; ++i) a[i] = *(const float4*)&sm[(r0 + i) * 520 + k];
#pragma unroll
    for (int p = 0; p < 3; ++p) {
      if (p == 2 && !has2) continue;
#pragma unroll
      for (int i = 0; i < 4; ++i) {
        int c = p * 256 + cg * 4 + i;
        float4 w = *(const float4*)&Wg[(size_t)c * Hsz + k];
        int ci = p * 4 + i;
#pragma unroll
        for (int r = 0; r < 4; ++r)
          acc[ci][r] += a[r].x * w.x + a[r].y * w.y + a[r].z * w.z + a[r].w * w.w;
      }
    }
  }
  __syncthreads();
#pragma unroll
  for (int p = 0; p < 3; ++p) {
    if (p == 2 && !has2) continue;
#pragma unroll
    for (int i = 0; i < 4; ++i) {
      int c = p * 256 + cg * 4 + i;
      float bgc = bg[c];
#pragma unroll
      for (int r = 0; r < 4; ++r) sm[(r0 + r) * 600 + c] = acc[p * 4 + i][r] + bgc;
    }
  }
  __syncthreads();
  int wv = threadIdx.x >> 6, ln = threadIdx.x & 63;
  for (int r = wv; r < 16; r += 4) {
    float* row = sm + r * 600;
    float mx = -1e30f;
    for (int c = ln; c < 600; c += 64) mx = fmaxf(mx, row[c]);
#pragma unroll
    for (int off = 32; off > 0; off >>= 1) mx = fmaxf(mx, __shfl_xor(mx, off));
    float ssum = 0.f;
    for (int c = ln; c < 600; c += 64) {
      float ex = __expf(row[c] - mx);
      row[c] = ex;
      ssum += ex;
    }
#pragma unroll
    for (int off = 32; off > 0; off >>= 1) ssum += __shfl_xor(ssum, off);
    float inv = __fdividef(1.f, ssum);
    float* op = out + (size_t)(m0 + r) * 600;
    for (int c = ln; c < 600; c += 64) op[c] = row[c] * inv;
  }
}

extern "C" void kernel_launch(void* const* d_in, const int* in_sizes, int n_in,
                              void* d_out, int out_size, void* d_ws, size_t ws_size,
                              hipStream_t stream) {
  const float* bH = (const float*)d_in[0];
  const int* text = (const int*)d_in[1];  // harness converts int64 -> int32
  const float* Wi2h = (const float*)d_in[2];
  const float* Wh2h = (const float*)d_in[3];
  const float* bh2h = (const float*)d_in[4];
  const float* Wsc = (const float*)d_in[5];
  const float* Wih = (const float*)d_in[6];
  const float* Whh = (const float*)d_in[7];
  const float* bih = (const float*)d_in[8];
  const float* bhh = (const float*)d_in[9];
  const float* Wg = (const float*)d_in[10];
  const float* bg = (const float*)d_in[11];
  float* out = (float*)d_out;

  char* ws = (char*)d_ws;
  size_t off = 0;
  __half* Hp16 = (__half*)(ws + off);  off += (size_t)Bsz * Ssz * Hsz * 2;   // 67.1 MB
  __half* bH16 = (__half*)(ws + off);  off += (size_t)Bsz * Ssz * Vsz * 2;   // 78.6 MB
  __half* hid16 = (__half*)(ws + off); off += (size_t)Tsz * Bsz * Hsz * 2;   // 15.9 MB
  float* WiT = (float*)(ws + off);     off += (size_t)600 * 512 * 4;         // 1.2 MB
  float* h_pp = (float*)(ws + off);    off += (size_t)2 * Bsz * Hsz * 4;     // 0.5 MB
  float* pp = (float*)(ws + off);      off += (size_t)Bsz * Hsz * 4;         // 0.25 MB
  float* ev = (float*)(ws + off);      off += (size_t)Bsz * Ssz * 4;         // 0.25 MB
  float* ctx = (float*)(ws + off);     off += (size_t)Bsz * Vsz * 4;         // 0.3 MB
  off = (off + 127) & ~(size_t)127;
  unsigned* flags = (unsigned*)(ws + off);  // 416 lines x 128 B = 53 KB

  hipMemsetAsync(flags, 0, (size_t)416 * FSTR * sizeof(unsigned), stream);

  k_wt<<<dim3(25, 16), 256, 0, stream>>>(Wi2h, WiT);
  k_hp<<<(Bsz * Ssz) / 16, 256, 0, stream>>>(bH, WiT, Hp16, bH16);
  k_step<<<NBLK, 256, 0, stream>>>(bH16, Hp16, Wh2h, bh2h, Wsc, Wih, Whh,
                                   bih, bhh, text, h_pp, hid16, pp, ev, ctx,
                                   flags);
  k_gen<<<(Bsz * Tsz) / 16, 256, 0, stream>>>(hid16, Wg, bg, out);
}

// Round 9
// 29003.146 us; speedup vs baseline: 4.0378x; 1.0048x over previous
//
#include <hip/hip_runtime.h>
#include <hip/hip_fp16.h>
#include <stdint.h>

#define Bsz 128
#define Ssz 512
#define Vsz 600
#define Hsz 512
#define Tsz 121

// branch-free 6-op tanh: tanh(x) = 1 - 2/(1 + e^{2x}); exact at +/-inf, ~1e-6 abs err
__device__ __forceinline__ float fast_tanh(float x) {
  float e = __expf(x + x);
  return 1.0f - __fdividef(2.0f, 1.0f + e);
}

// ---------------- one-time: WiT[k][c] = Wi[c][k]  (600x512 transpose) ----------------
__global__ __launch_bounds__(256) void k_wt(const float* __restrict__ Wi,
                                            float* __restrict__ WiT) {
  __shared__ float T[32][25];
  int k0 = blockIdx.x * 24, c0 = blockIdx.y * 32;
  for (int idx = threadIdx.x; idx < 32 * 24; idx += 256) {
    int i = idx / 24, j = idx - i * 24;
    T[i][j] = Wi[(size_t)(c0 + i) * 600 + k0 + j];
  }
  __syncthreads();
  for (int idx = threadIdx.x; idx < 24 * 32; idx += 256) {
    int j = idx >> 5, i = idx & 31;
    WiT[(size_t)(k0 + j) * 512 + c0 + i] = T[i][j];
  }
}

// ---- one-time: Hp16 = (batch_H @ W_i2h^T) fp16 [b][s][k], bH16 = batch_H fp16 [b][s][v] ----
__global__ __launch_bounds__(256) void k_hp(const float* __restrict__ bH,
                                            const float* __restrict__ WiT,
                                            __half* __restrict__ Hp,
                                            __half* __restrict__ bH16) {
  __shared__ __align__(16) float As[16][604];
  int m0 = blockIdx.x * 16;
  for (int idx = threadIdx.x; idx < 16 * 600; idx += 256) {
    int r = idx / 600, k = idx - r * 600;
    As[r][k] = bH[(size_t)(m0 + r) * 600 + k];
  }
  __syncthreads();
  for (int idx = threadIdx.x; idx < 16 * 300; idx += 256) {
    int r = idx / 300, v2 = (idx - r * 300) * 2;
    __half2 h = __floats2half2_rn(As[r][v2], As[r][v2 + 1]);
    *(__half2*)&bH16[(size_t)(m0 + r) * 600 + v2] = h;
  }
  int rg = threadIdx.x & 3, cg = threadIdx.x >> 2;
  int r0 = rg * 4;
  for (int pass = 0; pass < 2; ++pass) {
    int c0 = pass * 256 + cg * 4;
    float acc[4][4] = {};
    for (int k = 0; k < 600; k += 4) {
      float4 w0 = *(const float4*)&WiT[(size_t)(k + 0) * 512 + c0];
      float4 w1 = *(const float4*)&WiT[(size_t)(k + 1) * 512 + c0];
      float4 w2 = *(const float4*)&WiT[(size_t)(k + 2) * 512 + c0];
      float4 w3 = *(const float4*)&WiT[(size_t)(k + 3) * 512 + c0];
#pragma unroll
      for (int i = 0; i < 4; ++i) {
        float4 a = *(const float4*)&As[r0 + i][k];
        acc[i][0] += a.x * w0.x + a.y * w1.x + a.z * w2.x + a.w * w3.x;
        acc[i][1] += a.x * w0.y + a.y * w1.y + a.z * w2.y + a.w * w3.y;
        acc[i][2] += a.x * w0.z + a.y * w1.z + a.z * w2.z + a.w * w3.z;
        acc[i][3] += a.x * w0.w + a.y * w1.w + a.z * w2.w + a.w * w3.w;
      }
    }
#pragma unroll
    for (int i = 0; i < 4; ++i) {
      __half2 p01 = __floats2half2_rn(acc[i][0], acc[i][1]);
      __half2 p23 = __floats2half2_rn(acc[i][2], acc[i][3]);
      union { __half2 h2[2]; float2 f2; } u;
      u.h2[0] = p01; u.h2[1] = p23;
      *(float2*)&Hp[(size_t)(m0 + r0 + i) * Hsz + c0] = u.f2;
    }
  }
}

// ---------------- pp = h_prev @ W_h2h^T + b_h2h ----------------
// grid dim3(Bsz, 4): (batch, j-quad of 128); 256 thr = 128 j-lanes x 2 k-halves
__global__ __launch_bounds__(256) void k_pp(const float* __restrict__ hprev,
                                            const float* __restrict__ W,
                                            const float* __restrict__ bias,
                                            float* __restrict__ pp) {
  __shared__ __align__(16) float hs[512];
  __shared__ float part[128];
  int b = blockIdx.x, jq = blockIdx.y;
  int tid = threadIdx.x;
  hs[tid] = hprev[b * Hsz + tid];
  hs[tid + 256] = hprev[b * Hsz + 256 + tid];
  __syncthreads();
  int jl = tid & 127, kh = tid >> 7;
  int j = jq * 128 + jl;
  const float* wrow = W + (size_t)j * Hsz + kh * 256;
  const float* hp = hs + kh * 256;
  float acc = 0.f;
#pragma unroll 4
  for (int k = 0; k < 256; k += 4) {
    float4 w = *(const float4*)(wrow + k);
    float4 h4 = *(const float4*)(hp + k);
    acc += w.x * h4.x + w.y * h4.y + w.z * h4.z + w.w * h4.w;
  }
  if (kh == 1) part[jl] = acc;
  __syncthreads();
  if (kh == 0) pp[b * Hsz + j] = acc + part[jl] + bias[j];
}

// ---------------- e[b,s] = Wsc . tanh(Hp[b,s,:] + pp[b,:]) ----------------
// 512 blocks (b x 4 s-tiles of 128), 512 thr = 8 waves x 16 s each; lane owns 8 k
__global__ __launch_bounds__(512) void k_e(const __half* __restrict__ Hp,
                                           const float* __restrict__ pp,
                                           const float* __restrict__ Wsc,
                                           float* __restrict__ ev) {
  __shared__ __align__(16) float pps[512];
  __shared__ __align__(16) float wss[512];
  int b = blockIdx.x >> 2, tile = blockIdx.x & 3;
  int tid = threadIdx.x;
  pps[tid] = pp[b * Hsz + tid];
  wss[tid] = Wsc[tid];
  __syncthreads();
  int wv = tid >> 6, ln = tid & 63;
  float p8[8], w8[8];
  {
    float4 pa = *(const float4*)&pps[ln * 8];
    float4 pb = *(const float4*)&pps[ln * 8 + 4];
    float4 wa = *(const float4*)&wss[ln * 8];
    float4 wb = *(const float4*)&wss[ln * 8 + 4];
    p8[0] = pa.x; p8[1] = pa.y; p8[2] = pa.z; p8[3] = pa.w;
    p8[4] = pb.x; p8[5] = pb.y; p8[6] = pb.z; p8[7] = pb.w;
    w8[0] = wa.x; w8[1] = wa.y; w8[2] = wa.z; w8[3] = wa.w;
    w8[4] = wb.x; w8[5] = wb.y; w8[6] = wb.z; w8[7] = wb.w;
  }
  int sbase = tile * 128 + wv * 16;
  const __half* hbase = Hp + ((size_t)b * Ssz + sbase) * Hsz + ln * 8;
#pragma unroll 4
  for (int it = 0; it < 16; ++it) {
    float4 raw = *(const float4*)(hbase + (size_t)it * Hsz);
    const __half2* h2p = (const __half2*)&raw;
    float2 f0 = __half22float2(h2p[0]);
    float2 f1 = __half22float2(h2p[1]);
    float2 f2 = __half22float2(h2p[2]);
    float2 f3 = __half22float2(h2p[3]);
    float acc = w8[0] * fast_tanh(f0.x + p8[0]);
    acc += w8[1] * fast_tanh(f0.y + p8[1]);
    acc += w8[2] * fast_tanh(f1.x + p8[2]);
    acc += w8[3] * fast_tanh(f1.y + p8[3]);
    acc += w8[4] * fast_tanh(f2.x + p8[4]);
    acc += w8[5] * fast_tanh(f2.y + p8[5]);
    acc += w8[6] * fast_tanh(f3.x + p8[6]);
    acc += w8[7] * fast_tanh(f3.y + p8[7]);
#pragma unroll
    for (int off = 32; off > 0; off >>= 1) acc += __shfl_xor(acc, off);
    if (ln == 0) ev[b * Ssz + sbase + it] = acc;
  }
}

// ---------------- softmax(e) then ctx = alpha @ bH16 ----------------
// 512 blocks (b x 4 v-chunks of 150), 512 thr = 8 waves (s-groups of 64)
__global__ __launch_bounds__(512) void k_ctx(const __half* __restrict__ bH16,
                                             const float* __restrict__ ev,
                                             float* __restrict__ ctx) {
  __shared__ __align__(16) float al[512];
  __shared__ float red[16];
  __shared__ float part[7][152];
  int b = blockIdx.x >> 2, vq = blockIdx.x & 3;
  int tid = threadIdx.x;
  int wv = tid >> 6, ln = tid & 63;
  float e = ev[b * Ssz + tid];
  float m = e;
#pragma unroll
  for (int off = 32; off > 0; off >>= 1) m = fmaxf(m, __shfl_xor(m, off));
  if (ln == 0) red[wv] = m;
  __syncthreads();
  m = fmaxf(fmaxf(fmaxf(red[0], red[1]), fmaxf(red[2], red[3])),
            fmaxf(fmaxf(red[4], red[5]), fmaxf(red[6], red[7])));
  float x = __expf(e - m);
  float sum = x;
#pragma unroll
  for (int off = 32; off > 0; off >>= 1) sum += __shfl_xor(sum, off);
  if (ln == 0) red[8 + wv] = sum;
  __syncthreads();
  sum = (red[8] + red[9]) + (red[10] + red[11]) +
        (red[12] + red[13]) + (red[14] + red[15]);
  al[tid] = x * __fdividef(1.f, sum);
  __syncthreads();

  int v0 = vq * 150;
  const __half* base = bH16 + ((size_t)b * Ssz + (size_t)wv * 64) * Vsz + v0;
  const float* ap = al + wv * 64;
  float a0x = 0.f, a0y = 0.f, a1x = 0.f, a1y = 0.f;
  bool g = (ln < 11);
#pragma unroll 8
  for (int s2 = 0; s2 < 64; ++s2) {
    float a = ap[s2];
    const __half* row = base + (size_t)s2 * Vsz;
    float2 f = __half22float2(*(const __half2*)&row[2 * ln]);
    a0x += a * f.x;
    a0y += a * f.y;
    if (g) {
      float2 f2 = __half22float2(*(const __half2*)&row[128 + 2 * ln]);
      a1x += a * f2.x;
      a1y += a * f2.y;
    }
  }
  if (wv > 0) {
    part[wv - 1][2 * ln] = a0x;
    part[wv - 1][2 * ln + 1] = a0y;
    if (g) {
      part[wv - 1][128 + 2 * ln] = a1x;
      part[wv - 1][129 + 2 * ln] = a1y;
    }
  }
  __syncthreads();
  if (wv == 0) {
#pragma unroll
    for (int gi = 0; gi < 7; ++gi) {
      a0x += part[gi][2 * ln];
      a0y += part[gi][2 * ln + 1];
    }
    *(float2*)&ctx[b * Vsz + v0 + 2 * ln] = make_float2(a0x, a0y);
    if (g) {
#pragma unroll
      for (int gi = 0; gi < 7; ++gi) {
        a1x += part[gi][128 + 2 * ln];
        a1y += part[gi][129 + 2 * ln];
      }
      *(float2*)&ctx[b * Vsz + v0 + 128 + 2 * ln] = make_float2(a1x, a1y);
    }
  }
}

// ---------------- gates + LSTM pointwise ----------------
// 256 blocks x 512 thr: bt = 8 b's, jt = 32 j's (XCD-grouped), kh split x2
struct ShG { float xs[8][1112]; float4 part[8][32]; };

__global__ __launch_bounds__(512) void k_gates(
    const float* __restrict__ ctx, const float* __restrict__ hprev,
    const float* __restrict__ Wih, const float* __restrict__ Whh,
    const float* __restrict__ bih, const float* __restrict__ bhh,
    const int* __restrict__ text, int t,
    const float* __restrict__ cin, float* __restrict__ cout,
    float* __restrict__ hnextf, __half* __restrict__ hnext16) {
  __shared__ __align__(16) ShG G;
  const int bid = blockIdx.x, tid = threadIdx.x;
  const int jt = (bid & 7) * 2 + ((bid >> 3) & 1);  // XCD d%8 owns 2 j-tiles
  const int bt = bid >> 4;                           // [0,16)
  int b0 = bt * 8, j0 = jt * 32;
  for (int idx = tid; idx < 8 * 600; idx += 512) {
    int r = idx / 600, k = idx - r * 600;
    G.xs[r][k] = ctx[(b0 + r) * Vsz + k];
  }
  for (int idx = tid; idx < 8 * 512; idx += 512) {
    int r = idx >> 9, k = idx & 511;
    G.xs[r][600 + k] = hprev[(b0 + r) * Hsz + k];
  }
  __syncthreads();
  int bi = tid >> 6, jl = tid & 31, kh = (tid >> 5) & 1;
  int bb = b0 + bi, j = j0 + jl;
  float a0 = 0.f, a1 = 0.f, a2 = 0.f, a3 = 0.f;
  const float* xr = G.xs[bi];
  const float* w0 = Wih + (size_t)(0 * Hsz + j) * 1200 + kh * 300;
  const float* w1 = Wih + (size_t)(1 * Hsz + j) * 1200 + kh * 300;
  const float* w2 = Wih + (size_t)(2 * Hsz + j) * 1200 + kh * 300;
  const float* w3 = Wih + (size_t)(3 * Hsz + j) * 1200 + kh * 300;
  const float* xc = xr + kh * 300;
#pragma unroll 2
  for (int k = 0; k < 300; k += 4) {
    float4 x4 = *(const float4*)(xc + k);
    float4 q0 = *(const float4*)(w0 + k);
    a0 += x4.x * q0.x + x4.y * q0.y + x4.z * q0.z + x4.w * q0.w;
    float4 q1 = *(const float4*)(w1 + k);
    a1 += x4.x * q1.x + x4.y * q1.y + x4.z * q1.z + x4.w * q1.w;
    float4 q2 = *(const float4*)(w2 + k);
    a2 += x4.x * q2.x + x4.y * q2.y + x4.z * q2.z + x4.w * q2.w;
    float4 q3 = *(const float4*)(w3 + k);
    a3 += x4.x * q3.x + x4.y * q3.y + x4.z * q3.z + x4.w * q3.w;
  }
  const float* v0 = Whh + (size_t)(0 * Hsz + j) * Hsz + kh * 256;
  const float* v1 = Whh + (size_t)(1 * Hsz + j) * Hsz + kh * 256;
  const float* v2 = Whh + (size_t)(2 * Hsz + j) * Hsz + kh * 256;
  const float* v3 = Whh + (size_t)(3 * Hsz + j) * Hsz + kh * 256;
  const float* xh = xr + 600 + kh * 256;
#pragma unroll 2
  for (int k = 0; k < 256; k += 4) {
    float4 x4 = *(const float4*)(xh + k);
    float4 q0 = *(const float4*)(v0 + k);
    a0 += x4.x * q0.x + x4.y * q0.y + x4.z * q0.z + x4.w * q0.w;
    float4 q1 = *(const float4*)(v1 + k);
    a1 += x4.x * q1.x + x4.y * q1.y + x4.z * q1.z + x4.w * q1.w;
    float4 q2 = *(const float4*)(v2 + k);
    a2 += x4.x * q2.x + x4.y * q2.y + x4.z * q2.z + x4.w * q2.w;
    float4 q3 = *(const float4*)(v3 + k);
    a3 += x4.x * q3.x + x4.y * q3.y + x4.z * q3.z + x4.w * q3.w;
  }
  if (kh == 1) {
    int tk = (t == 0) ? 0 : text[bb * Tsz + (t - 1)];
    a0 += Wih[(size_t)(0 * Hsz + j) * 1200 + 600 + tk];
    a1 += Wih[(size_t)(1 * Hsz + j) * 1200 + 600 + tk];
    a2 += Wih[(size_t)(2 * Hsz + j) * 1200 + 600 + tk];
    a3 += Wih[(size_t)(3 * Hsz + j) * 1200 + 600 + tk];
    G.part[bi][jl] = make_float4(a0, a1, a2, a3);
  }
  __syncthreads();
  if (kh == 0) {
    float4 p = G.part[bi][jl];
    a0 += p.x + bih[j] + bhh[j];
    a1 += p.y + bih[512 + j] + bhh[512 + j];
    a2 += p.z + bih[1024 + j] + bhh[1024 + j];
    a3 += p.w + bih[1536 + j] + bhh[1536 + j];
    float ig = 1.f / (1.f + __expf(-a0));
    float fg = 1.f / (1.f + __expf(-a1));
    float gg = fast_tanh(a2);
    float og = 1.f / (1.f + __expf(-a3));
    float c = fg * cin[bb * Hsz + j] + ig * gg;
    float hN = og * fast_tanh(c);
    cout[bb * Hsz + j] = c;
    hnextf[bb * Hsz + j] = hN;
    hnext16[(size_t)bb * Hsz + j] = __float2half(hN);
  }
}

// ---------------- probs = softmax(hid16 @ W_gen^T + b_gen) ----------------
__global__ __launch_bounds__(256) void k_gen(const __half* __restrict__ hid16,
                                             const float* __restrict__ Wg,
                                             const float* __restrict__ bg,
                                             float* __restrict__ out) {
  __shared__ __align__(16) float sm[16 * 600];
  int m0 = blockIdx.x * 16;
  for (int idx = threadIdx.x; idx < 16 * 64; idx += 256) {
    int r = idx >> 6, k8 = (idx & 63) * 8;
    int m = m0 + r;
    int bb = m / Tsz, tt = m - bb * Tsz;
    float4 raw = *(const float4*)&hid16[((size_t)tt * Bsz + bb) * Hsz + k8];
    const __half2* h2p = (const __half2*)&raw;
    float2 f0 = __half22float2(h2p[0]);
    float2 f1 = __half22float2(h2p[1]);
    float2 f2 = __half22float2(h2p[2]);
    float2 f3 = __half22float2(h2p[3]);
    float* d = &sm[r * 520 + k8];
    d[0] = f0.x; d[1] = f0.y; d[2] = f1.x; d[3] = f1.y;
    d[4] = f2.x; d[5] = f2.y; d[6] = f3.x; d[7] = f3.y;
  }
  __syncthreads();
  int rg = threadIdx.x & 3, cg = threadIdx.x >> 2;
  int r0 = rg * 4;
  bool has2 = (cg < 22);
  float acc[12][4] = {};
  for (int k = 0; k < 512; k += 4) {
    float4 a[4];
#pragma unroll
    for (int i = 0; i < 4; ++i) a[i] = *(const float4*)&sm[(r0 + i) * 520 + k];
#pragma unroll
    for (int p = 0; p < 3; ++p) {
      if (p == 2 && !has2) continue;
#pragma unroll
      for (int i = 0; i < 4; ++i) {
        int c = p * 256 + cg * 4 + i;
        float4 w = *(const float4*)&Wg[(size_t)c * Hsz + k];
        int ci = p * 4 + i;
#pragma unroll
        for (int r = 0; r < 4; ++r)
          acc[ci][r] += a[r].x * w.x + a[r].y * w.y + a[r].z * w.z + a[r].w * w.w;
      }
    }
  }
  __syncthreads();
#pragma unroll
  for (int p = 0; p < 3; ++p) {
    if (p == 2 && !has2) continue;
#pragma unroll
    for (int i = 0; i < 4; ++i) {
      int c = p * 256 + cg * 4 + i;
      float bgc = bg[c];
#pragma unroll
      for (int r = 0; r < 4; ++r) sm[(r0 + r) * 600 + c] = acc[p * 4 + i][r] + bgc;
    }
  }
  __syncthreads();
  int wv = threadIdx.x >> 6, ln = threadIdx.x & 63;
  for (int r = wv; r < 16; r += 4) {
    float* row = sm + r * 600;
    float mx = -1e30f;
    for (int c = ln; c < 600; c += 64) mx = fmaxf(mx, row[c]);
#pragma unroll
    for (int off = 32; off > 0; off >>= 1) mx = fmaxf(mx, __shfl_xor(mx, off));
    float ssum = 0.f;
    for (int c = ln; c < 600; c += 64) {
      float ex = __expf(row[c] - mx);
      row[c] = ex;
      ssum += ex;
    }
#pragma unroll
    for (int off = 32; off > 0; off >>= 1) ssum += __shfl_xor(ssum, off);
    float inv = __fdividef(1.f, ssum);
    float* op = out + (size_t)(m0 + r) * 600;
    for (int c = ln; c < 600; c += 64) op[c] = row[c] * inv;
  }
}

extern "C" void kernel_launch(void* const* d_in, const int* in_sizes, int n_in,
                              void* d_out, int out_size, void* d_ws, size_t ws_size,
                              hipStream_t stream) {
  const float* bH = (const float*)d_in[0];
  const int* text = (const int*)d_in[1];  // harness converts int64 -> int32
  const float* Wi2h = (const float*)d_in[2];
  const float* Wh2h = (const float*)d_in[3];
  const float* bh2h = (const float*)d_in[4];
  const float* Wsc = (const float*)d_in[5];
  const float* Wih = (const float*)d_in[6];
  const float* Whh = (const float*)d_in[7];
  const float* bih = (const float*)d_in[8];
  const float* bhh = (const float*)d_in[9];
  const float* Wg = (const float*)d_in[10];
  const float* bg = (const float*)d_in[11];
  float* out = (float*)d_out;

  char* ws = (char*)d_ws;
  size_t off = 0;
  __half* Hp16 = (__half*)(ws + off);  off += (size_t)Bsz * Ssz * Hsz * 2;   // 67.1 MB
  __half* bH16 = (__half*)(ws + off);  off += (size_t)Bsz * Ssz * Vsz * 2;   // 78.6 MB
  __half* hid16 = (__half*)(ws + off); off += (size_t)Tsz * Bsz * Hsz * 2;   // 15.9 MB
  float* WiT = (float*)(ws + off);     off += (size_t)600 * 512 * 4;         // 1.2 MB
  float* h_pp = (float*)(ws + off);    off += (size_t)2 * Bsz * Hsz * 4;     // 0.5 MB
  float* cb = (float*)(ws + off);      off += (size_t)2 * Bsz * Hsz * 4;     // 0.5 MB
  float* pp = (float*)(ws + off);      off += (size_t)Bsz * Hsz * 4;         // 0.25 MB
  float* ev = (float*)(ws + off);      off += (size_t)Bsz * Ssz * 4;         // 0.25 MB
  float* ctx = (float*)(ws + off);     off += (size_t)Bsz * Vsz * 4;         // 0.3 MB

  hipMemsetAsync(h_pp, 0, (size_t)2 * Bsz * Hsz * 4, stream);
  hipMemsetAsync(cb, 0, (size_t)2 * Bsz * Hsz * 4, stream);

  k_wt<<<dim3(25, 16), 256, 0, stream>>>(Wi2h, WiT);
  k_hp<<<(Bsz * Ssz) / 16, 256, 0, stream>>>(bH, WiT, Hp16, bH16);

  for (int t = 0; t < Tsz; ++t) {
    const float* hprev = h_pp + (size_t)(t & 1) * Bsz * Hsz;
    float* hnextf = h_pp + (size_t)((t + 1) & 1) * Bsz * Hsz;
    const float* cin = cb + (size_t)(t & 1) * Bsz * Hsz;
    float* cout = cb + (size_t)((t + 1) & 1) * Bsz * Hsz;
    k_pp<<<dim3(Bsz, 4), 256, 0, stream>>>(hprev, Wh2h, bh2h, pp);
    k_e<<<Bsz * 4, 512, 0, stream>>>(Hp16, pp, Wsc, ev);
    k_ctx<<<Bsz * 4, 512, 0, stream>>>(bH16, ev, ctx);
    k_gates<<<256, 512, 0, stream>>>(ctx, hprev, Wih, Whh, bih, bhh, text, t,
                                     cin, cout, hnextf,
                                     hid16 + (size_t)t * Bsz * Hsz);
  }

  k_gen<<<(Bsz * Tsz) / 16, 256, 0, stream>>>(hid16, Wg, bg, out);
}

// Round 10
// 27492.682 us; speedup vs baseline: 4.2597x; 1.0549x over previous
//
#include <hip/hip_runtime.h>
#include <hip/hip_fp16.h>
#include <stdint.h>

#define Bsz 128
#define Ssz 512
#define Vsz 600
#define Hsz 512
#define Tsz 121

// branch-free 6-op tanh: tanh(x) = 1 - 2/(1 + e^{2x}); exact at +/-inf, ~1e-6 abs err
__device__ __forceinline__ float fast_tanh(float x) {
  float e = __expf(x + x);
  return 1.0f - __fdividef(2.0f, 1.0f + e);
}

// ---------------- one-time: WiT[k][c] = Wi[c][k]  (600x512 transpose) ----------------
__global__ __launch_bounds__(256) void k_wt(const float* __restrict__ Wi,
                                            float* __restrict__ WiT) {
  __shared__ float T[32][25];
  int k0 = blockIdx.x * 24, c0 = blockIdx.y * 32;
  for (int idx = threadIdx.x; idx < 32 * 24; idx += 256) {
    int i = idx / 24, j = idx - i * 24;
    T[i][j] = Wi[(size_t)(c0 + i) * 600 + k0 + j];
  }
  __syncthreads();
  for (int idx = threadIdx.x; idx < 24 * 32; idx += 256) {
    int j = idx >> 5, i = idx & 31;
    WiT[(size_t)(k0 + j) * 512 + c0 + i] = T[i][j];
  }
}

// ---- one-time: Hp16 = (batch_H @ W_i2h^T) fp16 [b][s][k]; bHT = batch_H^T fp16 [b][v][s] ----
__global__ __launch_bounds__(256) void k_hp(const float* __restrict__ bH,
                                            const float* __restrict__ WiT,
                                            __half* __restrict__ Hp,
                                            __half* __restrict__ bHT) {
  __shared__ __align__(16) float As[16][604];
  int m0 = blockIdx.x * 16;
  for (int idx = threadIdx.x; idx < 16 * 600; idx += 256) {
    int r = idx / 600, k = idx - r * 600;
    As[r][k] = bH[(size_t)(m0 + r) * 600 + k];
  }
  __syncthreads();
  // transposed fp16 copy: bHT[b][v][s0..s0+15]
  {
    int b = blockIdx.x >> 5, s0 = (blockIdx.x & 31) * 16;
    for (int v = threadIdx.x; v < 600; v += 256) {
      __half hbuf[16];
#pragma unroll
      for (int r = 0; r < 16; ++r) hbuf[r] = __float2half(As[r][v]);
      float4* dst = (float4*)&bHT[((size_t)b * 600 + v) * 512 + s0];
      dst[0] = ((float4*)hbuf)[0];
      dst[1] = ((float4*)hbuf)[1];
    }
  }
  int rg = threadIdx.x & 3, cg = threadIdx.x >> 2;
  int r0 = rg * 4;
  for (int pass = 0; pass < 2; ++pass) {
    int c0 = pass * 256 + cg * 4;
    float acc[4][4] = {};
    for (int k = 0; k < 600; k += 4) {
      float4 w0 = *(const float4*)&WiT[(size_t)(k + 0) * 512 + c0];
      float4 w1 = *(const float4*)&WiT[(size_t)(k + 1) * 512 + c0];
      float4 w2 = *(const float4*)&WiT[(size_t)(k + 2) * 512 + c0];
      float4 w3 = *(const float4*)&WiT[(size_t)(k + 3) * 512 + c0];
#pragma unroll
      for (int i = 0; i < 4; ++i) {
        float4 a = *(const float4*)&As[r0 + i][k];
        acc[i][0] += a.x * w0.x + a.y * w1.x + a.z * w2.x + a.w * w3.x;
        acc[i][1] += a.x * w0.y + a.y * w1.y + a.z * w2.y + a.w * w3.y;
        acc[i][2] += a.x * w0.z + a.y * w1.z + a.z * w2.z + a.w * w3.z;
        acc[i][3] += a.x * w0.w + a.y * w1.w + a.z * w2.w + a.w * w3.w;
      }
    }
#pragma unroll
    for (int i = 0; i < 4; ++i) {
      __half2 p01 = __floats2half2_rn(acc[i][0], acc[i][1]);
      __half2 p23 = __floats2half2_rn(acc[i][2], acc[i][3]);
      union { __half2 h2[2]; float2 f2; } u;
      u.h2[0] = p01; u.h2[1] = p23;
      *(float2*)&Hp[(size_t)(m0 + r0 + i) * Hsz + c0] = u.f2;
    }
  }
}

// ---------------- pp = h_prev @ W_h2h^T + b_h2h ----------------
// grid dim3(Bsz, 4): (batch, j-quad of 128); 256 thr = 128 j-lanes x 2 k-halves
__global__ __launch_bounds__(256) void k_pp(const float* __restrict__ hprev,
                                            const float* __restrict__ W,
                                            const float* __restrict__ bias,
                                            float* __restrict__ pp) {
  __shared__ __align__(16) float hs[512];
  __shared__ float part[128];
  int b = blockIdx.x, jq = blockIdx.y;
  int tid = threadIdx.x;
  hs[tid] = hprev[b * Hsz + tid];
  hs[tid + 256] = hprev[b * Hsz + 256 + tid];
  __syncthreads();
  int jl = tid & 127, kh = tid >> 7;
  int j = jq * 128 + jl;
  const float* wrow = W + (size_t)j * Hsz + kh * 256;
  const float* hp = hs + kh * 256;
  float acc = 0.f;
#pragma unroll 4
  for (int k = 0; k < 256; k += 4) {
    float4 w = *(const float4*)(wrow + k);
    float4 h4 = *(const float4*)(hp + k);
    acc += w.x * h4.x + w.y * h4.y + w.z * h4.z + w.w * h4.w;
  }
  if (kh == 1) part[jl] = acc;
  __syncthreads();
  if (kh == 0) pp[b * Hsz + j] = acc + part[jl] + bias[j];
}

// ---------------- e[b,s] = Wsc . tanh(Hp[b,s,:] + pp[b,:]) ----------------
// 512 blocks (b x 4 s-tiles of 128), 512 thr: thread owns (s, k-quarter of 128)
// per-lane-contiguous rows -> 64 cachelines in flight per wave instruction
__global__ __launch_bounds__(512) void k_e(const __half* __restrict__ Hp,
                                           const float* __restrict__ pp,
                                           const float* __restrict__ Wsc,
                                           float* __restrict__ ev) {
  __shared__ __align__(16) float pps[512];
  __shared__ __align__(16) float wss[512];
  __shared__ float part[4][128];
  int b = blockIdx.x >> 2, tile = blockIdx.x & 3;
  int tid = threadIdx.x;
  pps[tid] = pp[b * Hsz + tid];
  wss[tid] = Wsc[tid];
  __syncthreads();
  int sl = tid & 127, kq = tid >> 7;
  int s = tile * 128 + sl;
  const __half* hrow = Hp + ((size_t)b * Ssz + s) * Hsz + kq * 128;
  const float* pk = pps + kq * 128;
  const float* wk = wss + kq * 128;
  float acc = 0.f;
#pragma unroll 8
  for (int k = 0; k < 128; k += 8) {
    float4 raw = *(const float4*)(hrow + k);
    const __half2* h2p = (const __half2*)&raw;
    float2 f0 = __half22float2(h2p[0]);
    float2 f1 = __half22float2(h2p[1]);
    float2 f2 = __half22float2(h2p[2]);
    float2 f3 = __half22float2(h2p[3]);
    acc += wk[k + 0] * fast_tanh(f0.x + pk[k + 0]);
    acc += wk[k + 1] * fast_tanh(f0.y + pk[k + 1]);
    acc += wk[k + 2] * fast_tanh(f1.x + pk[k + 2]);
    acc += wk[k + 3] * fast_tanh(f1.y + pk[k + 3]);
    acc += wk[k + 4] * fast_tanh(f2.x + pk[k + 4]);
    acc += wk[k + 5] * fast_tanh(f2.y + pk[k + 5]);
    acc += wk[k + 6] * fast_tanh(f3.x + pk[k + 6]);
    acc += wk[k + 7] * fast_tanh(f3.y + pk[k + 7]);
  }
  part[kq][sl] = acc;
  __syncthreads();
  if (kq == 0)
    ev[b * Ssz + s] = (part[0][sl] + part[1][sl]) + (part[2][sl] + part[3][sl]);
}

// ---------------- softmax(e) then ctx = alpha @ bHT ----------------
// grid dim3(Bsz, 3): (batch, v-chunk of 200); 256 thr; thread owns v, reads own 1KB row
__global__ __launch_bounds__(256) void k_ctx(const __half* __restrict__ bHT,
                                             const float* __restrict__ ev,
                                             float* __restrict__ ctx) {
  __shared__ __align__(16) float al[512];
  __shared__ float red[8];
  int b = blockIdx.x, vc = blockIdx.y;
  int tid = threadIdx.x, wv = tid >> 6, ln = tid & 63;
  float e0 = ev[b * Ssz + tid], e1 = ev[b * Ssz + 256 + tid];
  float m = fmaxf(e0, e1);
#pragma unroll
  for (int off = 32; off > 0; off >>= 1) m = fmaxf(m, __shfl_xor(m, off));
  if (ln == 0) red[wv] = m;
  __syncthreads();
  m = fmaxf(fmaxf(red[0], red[1]), fmaxf(red[2], red[3]));
  float x0 = __expf(e0 - m), x1 = __expf(e1 - m);
  float sum = x0 + x1;
#pragma unroll
  for (int off = 32; off > 0; off >>= 1) sum += __shfl_xor(sum, off);
  if (ln == 0) red[4 + wv] = sum;
  __syncthreads();
  sum = (red[4] + red[5]) + (red[6] + red[7]);
  float inv = __fdividef(1.f, sum);
  al[tid] = x0 * inv;
  al[tid + 256] = x1 * inv;
  __syncthreads();
  int v = vc * 200 + tid;
  if (tid < 200) {
    const __half* row = bHT + ((size_t)b * Vsz + v) * Ssz;
    float a0 = 0.f, a1 = 0.f, a2 = 0.f, a3 = 0.f;
#pragma unroll 8
    for (int s = 0; s < Ssz; s += 8) {
      float4 raw = *(const float4*)(row + s);
      const __half2* h2p = (const __half2*)&raw;
      float2 f0 = __half22float2(h2p[0]);
      float2 f1 = __half22float2(h2p[1]);
      float2 f2 = __half22float2(h2p[2]);
      float2 f3 = __half22float2(h2p[3]);
      float4 aa = *(const float4*)&al[s];
      float4 ab = *(const float4*)&al[s + 4];
      a0 += aa.x * f0.x + aa.y * f0.y;
      a1 += aa.z * f1.x + aa.w * f1.y;
      a2 += ab.x * f2.x + ab.y * f2.y;
      a3 += ab.z * f3.x + ab.w * f3.y;
    }
    ctx[b * Vsz + v] = (a0 + a1) + (a2 + a3);
  }
}

// ---------------- gates + LSTM pointwise ----------------
// 256 blocks x 512 thr: bt = 8 b's, jt = 32 j's (XCD-grouped), kh split x2
struct ShG { float xs[8][1112]; float4 part[8][32]; };

__global__ __launch_bounds__(512) void k_gates(
    const float* __restrict__ ctx, const float* __restrict__ hprev,
    const float* __restrict__ Wih, const float* __restrict__ Whh,
    const float* __restrict__ bih, const float* __restrict__ bhh,
    const int* __restrict__ text, int t,
    const float* __restrict__ cin, float* __restrict__ cout,
    float* __restrict__ hnextf, __half* __restrict__ hnext16) {
  __shared__ __align__(16) ShG G;
  const int bid = blockIdx.x, tid = threadIdx.x;
  const int jt = (bid & 7) * 2 + ((bid >> 3) & 1);  // XCD d%8 owns 2 j-tiles
  const int bt = bid >> 4;                           // [0,16)
  int b0 = bt * 8, j0 = jt * 32;
  for (int idx = tid; idx < 8 * 600; idx += 512) {
    int r = idx / 600, k = idx - r * 600;
    G.xs[r][k] = ctx[(b0 + r) * Vsz + k];
  }
  for (int idx = tid; idx < 8 * 512; idx += 512) {
    int r = idx >> 9, k = idx & 511;
    G.xs[r][600 + k] = hprev[(b0 + r) * Hsz + k];
  }
  __syncthreads();
  int bi = tid >> 6, jl = tid & 31, kh = (tid >> 5) & 1;
  int bb = b0 + bi, j = j0 + jl;
  float a0 = 0.f, a1 = 0.f, a2 = 0.f, a3 = 0.f;
  const float* xr = G.xs[bi];
  const float* w0 = Wih + (size_t)(0 * Hsz + j) * 1200 + kh * 300;
  const float* w1 = Wih + (size_t)(1 * Hsz + j) * 1200 + kh * 300;
  const float* w2 = Wih + (size_t)(2 * Hsz + j) * 1200 + kh * 300;
  const float* w3 = Wih + (size_t)(3 * Hsz + j) * 1200 + kh * 300;
  const float* xc = xr + kh * 300;
#pragma unroll 2
  for (int k = 0; k < 300; k += 4) {
    float4 x4 = *(const float4*)(xc + k);
    float4 q0 = *(const float4*)(w0 + k);
    a0 += x4.x * q0.x + x4.y * q0.y + x4.z * q0.z + x4.w * q0.w;
    float4 q1 = *(const float4*)(w1 + k);
    a1 += x4.x * q1.x + x4.y * q1.y + x4.z * q1.z + x4.w * q1.w;
    float4 q2 = *(const float4*)(w2 + k);
    a2 += x4.x * q2.x + x4.y * q2.y + x4.z * q2.z + x4.w * q2.w;
    float4 q3 = *(const float4*)(w3 + k);
    a3 += x4.x * q3.x + x4.y * q3.y + x4.z * q3.z + x4.w * q3.w;
  }
  const float* v0 = Whh + (size_t)(0 * Hsz + j) * Hsz + kh * 256;
  const float* v1 = Whh + (size_t)(1 * Hsz + j) * Hsz + kh * 256;
  const float* v2 = Whh + (size_t)(2 * Hsz + j) * Hsz + kh * 256;
  const float* v3 = Whh + (size_t)(3 * Hsz + j) * Hsz + kh * 256;
  const float* xh = xr + 600 + kh * 256;
#pragma unroll 2
  for (int k = 0; k < 256; k += 4) {
    float4 x4 = *(const float4*)(xh + k);
    float4 q0 = *(const float4*)(v0 + k);
    a0 += x4.x * q0.x + x4.y * q0.y + x4.z * q0.z + x4.w * q0.w;
    float4 q1 = *(const float4*)(v1 + k);
    a1 += x4.x * q1.x + x4.y * q1.y + x4.z * q1.z + x4.w * q1.w;
    float4 q2 = *(const float4*)(v2 + k);
    a2 += x4.x * q2.x + x4.y * q2.y + x4.z * q2.z + x4.w * q2.w;
    float4 q3 = *(const float4*)(v3 + k);
    a3 += x4.x * q3.x + x4.y * q3.y + x4.z * q3.z + x4.w * q3.w;
  }
  if (kh == 1) {
    int tk = (t == 0) ? 0 : text[bb * Tsz + (t - 1)];
    a0 += Wih[(size_t)(0 * Hsz + j) * 1200 + 600 + tk];
    a1 += Wih[(size_t)(1 * Hsz + j) * 1200 + 600 + tk];
    a2 += Wih[(size_t)(2 * Hsz + j) * 1200 + 600 + tk];
    a3 += Wih[(size_t)(3 * Hsz + j) * 1200 + 600 + tk];
    G.part[bi][jl] = make_float4(a0, a1, a2, a3);
  }
  __syncthreads();
  if (kh == 0) {
    float4 p = G.part[bi][jl];
    a0 += p.x + bih[j] + bhh[j];
    a1 += p.y + bih[512 + j] + bhh[512 + j];
    a2 += p.z + bih[1024 + j] + bhh[1024 + j];
    a3 += p.w + bih[1536 + j] + bhh[1536 + j];
    float ig = 1.f / (1.f + __expf(-a0));
    float fg = 1.f / (1.f + __expf(-a1));
    float gg = fast_tanh(a2);
    float og = 1.f / (1.f + __expf(-a3));
    float c = fg * cin[bb * Hsz + j] + ig * gg;
    float hN = og * fast_tanh(c);
    cout[bb * Hsz + j] = c;
    hnextf[bb * Hsz + j] = hN;
    hnext16[(size_t)bb * Hsz + j] = __float2half(hN);
  }
}

// ---------------- probs = softmax(hid16 @ W_gen^T + b_gen) ----------------
__global__ __launch_bounds__(256) void k_gen(const __half* __restrict__ hid16,
                                             const float* __restrict__ Wg,
                                             const float* __restrict__ bg,
                                             float* __restrict__ out) {
  __shared__ __align__(16) float sm[16 * 600];
  int m0 = blockIdx.x * 16;
  for (int idx = threadIdx.x; idx < 16 * 64; idx += 256) {
    int r = idx >> 6, k8 = (idx & 63) * 8;
    int m = m0 + r;
    int bb = m / Tsz, tt = m - bb * Tsz;
    float4 raw = *(const float4*)&hid16[((size_t)tt * Bsz + bb) * Hsz + k8];
    const __half2* h2p = (const __half2*)&raw;
    float2 f0 = __half22float2(h2p[0]);
    float2 f1 = __half22float2(h2p[1]);
    float2 f2 = __half22float2(h2p[2]);
    float2 f3 = __half22float2(h2p[3]);
    float* d = &sm[r * 520 + k8];
    d[0] = f0.x; d[1] = f0.y; d[2] = f1.x; d[3] = f1.y;
    d[4] = f2.x; d[5] = f2.y; d[6] = f3.x; d[7] = f3.y;
  }
  __syncthreads();
  int rg = threadIdx.x & 3, cg = threadIdx.x >> 2;
  int r0 = rg * 4;
  bool has2 = (cg < 22);
  float acc[12][4] = {};
  for (int k = 0; k < 512; k += 4) {
    float4 a[4];
#pragma unroll
    for (int i = 0; i < 4; ++i) a[i] = *(const float4*)&sm[(r0 + i) * 520 + k];
#pragma unroll
    for (int p = 0; p < 3; ++p) {
      if (p == 2 && !has2) continue;
#pragma unroll
      for (int i = 0; i < 4; ++i) {
        int c = p * 256 + cg * 4 + i;
        float4 w = *(const float4*)&Wg[(size_t)c * Hsz + k];
        int ci = p * 4 + i;
#pragma unroll
        for (int r = 0; r < 4; ++r)
          acc[ci][r] += a[r].x * w.x + a[r].y * w.y + a[r].z * w.z + a[r].w * w.w;
      }
    }
  }
  __syncthreads();
#pragma unroll
  for (int p = 0; p < 3; ++p) {
    if (p == 2 && !has2) continue;
#pragma unroll
    for (int i = 0; i < 4; ++i) {
      int c = p * 256 + cg * 4 + i;
      float bgc = bg[c];
#pragma unroll
      for (int r = 0; r < 4; ++r) sm[(r0 + r) * 600 + c] = acc[p * 4 + i][r] + bgc;
    }
  }
  __syncthreads();
  int wv = threadIdx.x >> 6, ln = threadIdx.x & 63;
  for (int r = wv; r < 16; r += 4) {
    float* row = sm + r * 600;
    float mx = -1e30f;
    for (int c = ln; c < 600; c += 64) mx = fmaxf(mx, row[c]);
#pragma unroll
    for (int off = 32; off > 0; off >>= 1) mx = fmaxf(mx, __shfl_xor(mx, off));
    float ssum = 0.f;
    for (int c = ln; c < 600; c += 64) {
      float ex = __expf(row[c] - mx);
      row[c] = ex;
      ssum += ex;
    }
#pragma unroll
    for (int off = 32; off > 0; off >>= 1) ssum += __shfl_xor(ssum, off);
    float inv = __fdividef(1.f, ssum);
    float* op = out + (size_t)(m0 + r) * 600;
    for (int c = ln; c < 600; c += 64) op[c] = row[c] * inv;
  }
}

extern "C" void kernel_launch(void* const* d_in, const int* in_sizes, int n_in,
                              void* d_out, int out_size, void* d_ws, size_t ws_size,
                              hipStream_t stream) {
  const float* bH = (const float*)d_in[0];
  const int* text = (const int*)d_in[1];  // harness converts int64 -> int32
  const float* Wi2h = (const float*)d_in[2];
  const float* Wh2h = (const float*)d_in[3];
  const float* bh2h = (const float*)d_in[4];
  const float* Wsc = (const float*)d_in[5];
  const float* Wih = (const float*)d_in[6];
  const float* Whh = (const float*)d_in[7];
  const float* bih = (const float*)d_in[8];
  const float* bhh = (const float*)d_in[9];
  const float* Wg = (const float*)d_in[10];
  const float* bg = (const float*)d_in[11];
  float* out = (float*)d_out;

  char* ws = (char*)d_ws;
  size_t off = 0;
  __half* Hp16 = (__half*)(ws + off);  off += (size_t)Bsz * Ssz * Hsz * 2;   // 67.1 MB
  __half* bHT = (__half*)(ws + off);   off += (size_t)Bsz * Vsz * Ssz * 2;   // 78.6 MB
  __half* hid16 = (__half*)(ws + off); off += (size_t)Tsz * Bsz * Hsz * 2;   // 15.9 MB
  float* WiT = (float*)(ws + off);     off += (size_t)600 * 512 * 4;         // 1.2 MB
  float* h_pp = (float*)(ws + off);    off += (size_t)2 * Bsz * Hsz * 4;     // 0.5 MB
  float* cb = (float*)(ws + off);      off += (size_t)2 * Bsz * Hsz * 4;     // 0.5 MB
  float* pp = (float*)(ws + off);      off += (size_t)Bsz * Hsz * 4;         // 0.25 MB
  float* ev = (float*)(ws + off);      off += (size_t)Bsz * Ssz * 4;         // 0.25 MB
  float* ctx = (float*)(ws + off);     off += (size_t)Bsz * Vsz * 4;         // 0.3 MB

  hipMemsetAsync(h_pp, 0, (size_t)2 * Bsz * Hsz * 4, stream);
  hipMemsetAsync(cb, 0, (size_t)2 * Bsz * Hsz * 4, stream);

  k_wt<<<dim3(25, 16), 256, 0, stream>>>(Wi2h, WiT);
  k_hp<<<(Bsz * Ssz) / 16, 256, 0, stream>>>(bH, WiT, Hp16, bHT);

  for (int t = 0; t < Tsz; ++t) {
    const float* hprev = h_pp + (size_t)(t & 1) * Bsz * Hsz;
    float* hnextf = h_pp + (size_t)((t + 1) & 1) * Bsz * Hsz;
    const float* cin = cb + (size_t)(t & 1) * Bsz * Hsz;
    float* cout = cb + (size_t)((t + 1) & 1) * Bsz * Hsz;
    k_pp<<<dim3(Bsz, 4), 256, 0, stream>>>(hprev, Wh2h, bh2h, pp);
    k_e<<<Bsz * 4, 512, 0, stream>>>(Hp16, pp, Wsc, ev);
    k_ctx<<<dim3(Bsz, 3), 256, 0, stream>>>(bHT, ev, ctx);
    k_gates<<<256, 512, 0, stream>>>(ctx, hprev, Wih, Whh, bih, bhh, text, t,
                                     cin, cout, hnextf,
                                     hid16 + (size_t)t * Bsz * Hsz);
  }

  k_gen<<<(Bsz * Tsz) / 16, 256, 0, stream>>>(hid16, Wg, bg, out);
}

// Round 11
// 24510.725 us; speedup vs baseline: 4.7779x; 1.1217x over previous
//
#include <hip/hip_runtime.h>
#include <hip/hip_fp16.h>
#include <stdint.h>

#define Bsz 128
#define Ssz 512
#define Vsz 600
#define Hsz 512
#define Tsz 121

// branch-free 6-op tanh: tanh(x) = 1 - 2/(1 + e^{2x}); exact at +/-inf, ~1e-6 abs err
__device__ __forceinline__ float fast_tanh(float x) {
  float e = __expf(x + x);
  return 1.0f - __fdividef(2.0f, 1.0f + e);
}

// ---------------- one-time: WiT[k][c] = Wi[c][k]  (600x512 transpose) ----------------
__global__ __launch_bounds__(256) void k_wt(const float* __restrict__ Wi,
                                            float* __restrict__ WiT) {
  __shared__ float T[32][25];
  int k0 = blockIdx.x * 24, c0 = blockIdx.y * 32;
  for (int idx = threadIdx.x; idx < 32 * 24; idx += 256) {
    int i = idx / 24, j = idx - i * 24;
    T[i][j] = Wi[(size_t)(c0 + i) * 600 + k0 + j];
  }
  __syncthreads();
  for (int idx = threadIdx.x; idx < 24 * 32; idx += 256) {
    int j = idx >> 5, i = idx & 31;
    WiT[(size_t)(k0 + j) * 512 + c0 + i] = T[i][j];
  }
}

// ---- one-time: Hp16 = (batch_H @ W_i2h^T) fp16 [b][s][k]; bHT = batch_H^T fp16 [b][v][s] ----
__global__ __launch_bounds__(256) void k_hp(const float* __restrict__ bH,
                                            const float* __restrict__ WiT,
                                            __half* __restrict__ Hp,
                                            __half* __restrict__ bHT) {
  __shared__ __align__(16) float As[16][604];
  int m0 = blockIdx.x * 16;
  for (int idx = threadIdx.x; idx < 16 * 600; idx += 256) {
    int r = idx / 600, k = idx - r * 600;
    As[r][k] = bH[(size_t)(m0 + r) * 600 + k];
  }
  __syncthreads();
  // transposed fp16 copy: bHT[b][v][s0..s0+15]
  {
    int b = blockIdx.x >> 5, s0 = (blockIdx.x & 31) * 16;
    for (int v = threadIdx.x; v < 600; v += 256) {
      __half hbuf[16];
#pragma unroll
      for (int r = 0; r < 16; ++r) hbuf[r] = __float2half(As[r][v]);
      float4* dst = (float4*)&bHT[((size_t)b * 600 + v) * 512 + s0];
      dst[0] = ((float4*)hbuf)[0];
      dst[1] = ((float4*)hbuf)[1];
    }
  }
  int rg = threadIdx.x & 3, cg = threadIdx.x >> 2;
  int r0 = rg * 4;
  for (int pass = 0; pass < 2; ++pass) {
    int c0 = pass * 256 + cg * 4;
    float acc[4][4] = {};
    for (int k = 0; k < 600; k += 4) {
      float4 w0 = *(const float4*)&WiT[(size_t)(k + 0) * 512 + c0];
      float4 w1 = *(const float4*)&WiT[(size_t)(k + 1) * 512 + c0];
      float4 w2 = *(const float4*)&WiT[(size_t)(k + 2) * 512 + c0];
      float4 w3 = *(const float4*)&WiT[(size_t)(k + 3) * 512 + c0];
#pragma unroll
      for (int i = 0; i < 4; ++i) {
        float4 a = *(const float4*)&As[r0 + i][k];
        acc[i][0] += a.x * w0.x + a.y * w1.x + a.z * w2.x + a.w * w3.x;
        acc[i][1] += a.x * w0.y + a.y * w1.y + a.z * w2.y + a.w * w3.y;
        acc[i][2] += a.x * w0.z + a.y * w1.z + a.z * w2.z + a.w * w3.z;
        acc[i][3] += a.x * w0.w + a.y * w1.w + a.z * w2.w + a.w * w3.w;
      }
    }
#pragma unroll
    for (int i = 0; i < 4; ++i) {
      __half2 p01 = __floats2half2_rn(acc[i][0], acc[i][1]);
      __half2 p23 = __floats2half2_rn(acc[i][2], acc[i][3]);
      union { __half2 h2[2]; float2 f2; } u;
      u.h2[0] = p01; u.h2[1] = p23;
      *(float2*)&Hp[(size_t)(m0 + r0 + i) * Hsz + c0] = u.f2;
    }
  }
}

// ---------------- pp = h_prev @ W_h2h^T + b_h2h ----------------
// grid dim3(Bsz, 4) x 512 thr: 128 j-lanes x 4 k-quarters -> 16 waves/CU
__global__ __launch_bounds__(512, 4) void k_pp(const float* __restrict__ hprev,
                                               const float* __restrict__ W,
                                               const float* __restrict__ bias,
                                               float* __restrict__ pp) {
  __shared__ __align__(16) float hs[512];
  __shared__ float part[4][128];
  int b = blockIdx.x, jq = blockIdx.y;
  int tid = threadIdx.x;
  hs[tid] = hprev[b * Hsz + tid];
  __syncthreads();
  int jl = tid & 127, kq = tid >> 7;
  int j = jq * 128 + jl;
  const float* wrow = W + (size_t)j * Hsz + kq * 128;
  const float* hp = hs + kq * 128;
  float acc = 0.f;
#pragma unroll 8
  for (int k = 0; k < 128; k += 4) {
    float4 w = *(const float4*)(wrow + k);
    float4 h4 = *(const float4*)(hp + k);
    acc += w.x * h4.x + w.y * h4.y + w.z * h4.z + w.w * h4.w;
  }
  part[kq][jl] = acc;
  __syncthreads();
  if (kq == 0)
    pp[b * Hsz + j] = (part[0][jl] + part[1][jl]) + (part[2][jl] + part[3][jl]) + bias[j];
}

// ---------------- e[b,s] = Wsc . tanh(Hp[b,s,:] + pp[b,:]) ----------------
// 1024 blocks (b x 8 s-tiles of 64) x 512 thr: thread = (s, k-eighth of 64) -> 32 waves/CU
__global__ __launch_bounds__(512, 8) void k_e(const __half* __restrict__ Hp,
                                              const float* __restrict__ pp,
                                              const float* __restrict__ Wsc,
                                              float* __restrict__ ev) {
  __shared__ __align__(16) float pps[512];
  __shared__ __align__(16) float wss[512];
  __shared__ float part[8][64];
  int b = blockIdx.x >> 3, tile = blockIdx.x & 7;
  int tid = threadIdx.x;
  pps[tid] = pp[b * Hsz + tid];
  wss[tid] = Wsc[tid];
  __syncthreads();
  int sl = tid & 63, kq = tid >> 6;
  int s = tile * 64 + sl;
  const __half* hrow = Hp + ((size_t)b * Ssz + s) * Hsz + kq * 64;
  const float* pk = pps + kq * 64;
  const float* wk = wss + kq * 64;
  float acc = 0.f;
#pragma unroll
  for (int k = 0; k < 64; k += 8) {
    float4 raw = *(const float4*)(hrow + k);
    const __half2* h2p = (const __half2*)&raw;
    float2 f0 = __half22float2(h2p[0]);
    float2 f1 = __half22float2(h2p[1]);
    float2 f2 = __half22float2(h2p[2]);
    float2 f3 = __half22float2(h2p[3]);
    acc += wk[k + 0] * fast_tanh(f0.x + pk[k + 0]);
    acc += wk[k + 1] * fast_tanh(f0.y + pk[k + 1]);
    acc += wk[k + 2] * fast_tanh(f1.x + pk[k + 2]);
    acc += wk[k + 3] * fast_tanh(f1.y + pk[k + 3]);
    acc += wk[k + 4] * fast_tanh(f2.x + pk[k + 4]);
    acc += wk[k + 5] * fast_tanh(f2.y + pk[k + 5]);
    acc += wk[k + 6] * fast_tanh(f3.x + pk[k + 6]);
    acc += wk[k + 7] * fast_tanh(f3.y + pk[k + 7]);
  }
  part[kq][sl] = acc;
  __syncthreads();
  if (kq == 0) {
    float r = ((part[0][sl] + part[1][sl]) + (part[2][sl] + part[3][sl])) +
              ((part[4][sl] + part[5][sl]) + (part[6][sl] + part[7][sl]));
    ev[b * Ssz + s] = r;
  }
}

// ---------------- softmax(e) then ctx = alpha @ bHT ----------------
// grid dim3(Bsz, 10) x 512 thr: 60 v-lanes x 8 s-groups of 64 -> ~32 waves/CU
__global__ __launch_bounds__(512, 8) void k_ctx(const __half* __restrict__ bHT,
                                                const float* __restrict__ ev,
                                                float* __restrict__ ctx) {
  __shared__ __align__(16) float al[512];
  __shared__ float red[16];
  __shared__ float part[8][64];
  int b = blockIdx.x, vq = blockIdx.y;
  int tid = threadIdx.x, wv = tid >> 6, ln = tid & 63;
  float e = ev[b * Ssz + tid];
  float m = e;
#pragma unroll
  for (int off = 32; off > 0; off >>= 1) m = fmaxf(m, __shfl_xor(m, off));
  if (ln == 0) red[wv] = m;
  __syncthreads();
  m = fmaxf(fmaxf(fmaxf(red[0], red[1]), fmaxf(red[2], red[3])),
            fmaxf(fmaxf(red[4], red[5]), fmaxf(red[6], red[7])));
  float x = __expf(e - m);
  float sum = x;
#pragma unroll
  for (int off = 32; off > 0; off >>= 1) sum += __shfl_xor(sum, off);
  if (ln == 0) red[8 + wv] = sum;
  __syncthreads();
  sum = ((red[8] + red[9]) + (red[10] + red[11])) +
        ((red[12] + red[13]) + (red[14] + red[15]));
  al[tid] = x * __fdividef(1.f, sum);
  __syncthreads();

  int sg = wv, vl = ln;
  int v = vq * 60 + vl;
  int vv = v < 600 ? v : 599;  // clamp (lanes 60-63 discarded at store)
  const __half* row = bHT + ((size_t)b * Vsz + vv) * Ssz + sg * 64;
  const float* ap = al + sg * 64;
  float a0 = 0.f, a1 = 0.f, a2 = 0.f, a3 = 0.f;
#pragma unroll
  for (int s2 = 0; s2 < 64; s2 += 8) {
    float4 raw = *(const float4*)(row + s2);
    const __half2* h2p = (const __half2*)&raw;
    float2 f0 = __half22float2(h2p[0]);
    float2 f1 = __half22float2(h2p[1]);
    float2 f2 = __half22float2(h2p[2]);
    float2 f3 = __half22float2(h2p[3]);
    float4 aa = *(const float4*)&ap[s2];
    float4 ab = *(const float4*)&ap[s2 + 4];
    a0 += aa.x * f0.x + aa.y * f0.y;
    a1 += aa.z * f1.x + aa.w * f1.y;
    a2 += ab.x * f2.x + ab.y * f2.y;
    a3 += ab.z * f3.x + ab.w * f3.y;
  }
  part[sg][vl] = (a0 + a1) + (a2 + a3);
  __syncthreads();
  if (sg == 0 && vl < 60) {
    float r = ((part[0][vl] + part[1][vl]) + (part[2][vl] + part[3][vl])) +
              ((part[4][vl] + part[5][vl]) + (part[6][vl] + part[7][vl]));
    ctx[b * Vsz + v] = r;
  }
}

// ---------------- gates + LSTM pointwise ----------------
// 512 blocks x 512 thr: bt=32 (4 b's) x jt=16 (32 j's, XCD-grouped);
// thread = (bi, jl, kh, gh): gate-pair gh over k-half kh -> 16 waves/CU
struct ShG { float xs[4][1112]; float2 part[4][32][4]; };

__global__ __launch_bounds__(512, 2) void k_gates(
    const float* __restrict__ ctx, const float* __restrict__ hprev,
    const float* __restrict__ Wih, const float* __restrict__ Whh,
    const float* __restrict__ bih, const float* __restrict__ bhh,
    const int* __restrict__ text, int t,
    const float* __restrict__ cin, float* __restrict__ cout,
    float* __restrict__ hnextf, __half* __restrict__ hnext16) {
  __shared__ __align__(16) ShG G;
  const int bid = blockIdx.x, tid = threadIdx.x;
  const int jt = ((bid & 7) << 1) | ((bid >> 3) & 1);  // XCD d%8 owns 2 j-tiles
  const int bt = bid >> 4;                              // [0,32)
  int b0 = bt * 4, j0 = jt * 32;
  for (int idx = tid; idx < 4 * 600; idx += 512) {
    int r = idx / 600, k = idx - r * 600;
    G.xs[r][k] = ctx[(b0 + r) * Vsz + k];
  }
  for (int idx = tid; idx < 4 * 512; idx += 512) {
    int r = idx >> 9, k = idx & 511;
    G.xs[r][600 + k] = hprev[(b0 + r) * Hsz + k];
  }
  __syncthreads();
  int bi = tid >> 7, r = tid & 127;
  int jl = r >> 2, kh = (r >> 1) & 1, gh = r & 1;
  int bb = b0 + bi, j = j0 + jl;
  int ga = gh * 2, gb = gh * 2 + 1;
  float accA = 0.f, accB = 0.f;
  const float* xr = G.xs[bi];
  const float* wa = Wih + (size_t)(ga * Hsz + j) * 1200 + kh * 300;
  const float* wb = Wih + (size_t)(gb * Hsz + j) * 1200 + kh * 300;
  const float* xc = xr + kh * 300;
#pragma unroll 4
  for (int k = 0; k < 300; k += 4) {
    float4 x4 = *(const float4*)(xc + k);
    float4 qa = *(const float4*)(wa + k);
    accA += x4.x * qa.x + x4.y * qa.y + x4.z * qa.z + x4.w * qa.w;
    float4 qb = *(const float4*)(wb + k);
    accB += x4.x * qb.x + x4.y * qb.y + x4.z * qb.z + x4.w * qb.w;
  }
  const float* va = Whh + (size_t)(ga * Hsz + j) * Hsz + kh * 256;
  const float* vb = Whh + (size_t)(gb * Hsz + j) * Hsz + kh * 256;
  const float* xh = xr + 600 + kh * 256;
#pragma unroll 4
  for (int k = 0; k < 256; k += 4) {
    float4 x4 = *(const float4*)(xh + k);
    float4 qa = *(const float4*)(va + k);
    accA += x4.x * qa.x + x4.y * qa.y + x4.z * qa.z + x4.w * qa.w;
    float4 qb = *(const float4*)(vb + k);
    accB += x4.x * qb.x + x4.y * qb.y + x4.z * qb.z + x4.w * qb.w;
  }
  if (kh == 1) {
    int tk = (t == 0) ? 0 : text[bb * Tsz + (t - 1)];
    accA += Wih[(size_t)(ga * Hsz + j) * 1200 + 600 + tk];
    accB += Wih[(size_t)(gb * Hsz + j) * 1200 + 600 + tk];
  }
  G.part[bi][jl][kh * 2 + gh] = make_float2(accA, accB);
  __syncthreads();
  if (kh == 0 && gh == 0) {
    float2 p00 = G.part[bi][jl][0];  // kh0: gates 0,1
    float2 p01 = G.part[bi][jl][1];  // kh0: gates 2,3
    float2 p10 = G.part[bi][jl][2];  // kh1: gates 0,1
    float2 p11 = G.part[bi][jl][3];  // kh1: gates 2,3
    float g0 = p00.x + p10.x + bih[j] + bhh[j];
    float g1 = p00.y + p10.y + bih[512 + j] + bhh[512 + j];
    float g2 = p01.x + p11.x + bih[1024 + j] + bhh[1024 + j];
    float g3 = p01.y + p11.y + bih[1536 + j] + bhh[1536 + j];
    float ig = 1.f / (1.f + __expf(-g0));
    float fg = 1.f / (1.f + __expf(-g1));
    float gg = fast_tanh(g2);
    float og = 1.f / (1.f + __expf(-g3));
    float c = fg * cin[bb * Hsz + j] + ig * gg;
    float hN = og * fast_tanh(c);
    cout[bb * Hsz + j] = c;
    hnextf[bb * Hsz + j] = hN;
    hnext16[(size_t)bb * Hsz + j] = __float2half(hN);
  }
}

// ---------------- probs = softmax(hid16 @ W_gen^T + b_gen) ----------------
__global__ __launch_bounds__(256) void k_gen(const __half* __restrict__ hid16,
                                             const float* __restrict__ Wg,
                                             const float* __restrict__ bg,
                                             float* __restrict__ out) {
  __shared__ __align__(16) float sm[16 * 600];
  int m0 = blockIdx.x * 16;
  for (int idx = threadIdx.x; idx < 16 * 64; idx += 256) {
    int r = idx >> 6, k8 = (idx & 63) * 8;
    int m = m0 + r;
    int bb = m / Tsz, tt = m - bb * Tsz;
    float4 raw = *(const float4*)&hid16[((size_t)tt * Bsz + bb) * Hsz + k8];
    const __half2* h2p = (const __half2*)&raw;
    float2 f0 = __half22float2(h2p[0]);
    float2 f1 = __half22float2(h2p[1]);
    float2 f2 = __half22float2(h2p[2]);
    float2 f3 = __half22float2(h2p[3]);
    float* d = &sm[r * 520 + k8];
    d[0] = f0.x; d[1] = f0.y; d[2] = f1.x; d[3] = f1.y;
    d[4] = f2.x; d[5] = f2.y; d[6] = f3.x; d[7] = f3.y;
  }
  __syncthreads();
  int rg = threadIdx.x & 3, cg = threadIdx.x >> 2;
  int r0 = rg * 4;
  bool has2 = (cg < 22);
  float acc[12][4] = {};
  for (int k = 0; k < 512; k += 4) {
    float4 a[4];
#pragma unroll
    for (int i = 0; i < 4; ++i) a[i] = *(const float4*)&sm[(r0 + i) * 520 + k];
#pragma unroll
    for (int p = 0; p < 3; ++p) {
      if (p == 2 && !has2) continue;
#pragma unroll
      for (int i = 0; i < 4; ++i) {
        int c = p * 256 + cg * 4 + i;
        float4 w = *(const float4*)&Wg[(size_t)c * Hsz + k];
        int ci = p * 4 + i;
#pragma unroll
        for (int r = 0; r < 4; ++r)
          acc[ci][r] += a[r].x * w.x + a[r].y * w.y + a[r].z * w.z + a[r].w * w.w;
      }
    }
  }
  __syncthreads();
#pragma unroll
  for (int p = 0; p < 3; ++p) {
    if (p == 2 && !has2) continue;
#pragma unroll
    for (int i = 0; i < 4; ++i) {
      int c = p * 256 + cg * 4 + i;
      float bgc = bg[c];
#pragma unroll
      for (int r = 0; r < 4; ++r) sm[(r0 + r) * 600 + c] = acc[p * 4 + i][r] + bgc;
    }
  }
  __syncthreads();
  int wv = threadIdx.x >> 6, ln = threadIdx.x & 63;
  for (int r = wv; r < 16; r += 4) {
    float* row = sm + r * 600;
    float mx = -1e30f;
    for (int c = ln; c < 600; c += 64) mx = fmaxf(mx, row[c]);
#pragma unroll
    for (int off = 32; off > 0; off >>= 1) mx = fmaxf(mx, __shfl_xor(mx, off));
    float ssum = 0.f;
    for (int c = ln; c < 600; c += 64) {
      float ex = __expf(row[c] - mx);
      row[c] = ex;
      ssum += ex;
    }
#pragma unroll
    for (int off = 32; off > 0; off >>= 1) ssum += __shfl_xor(ssum, off);
    float inv = __fdividef(1.f, ssum);
    float* op = out + (size_t)(m0 + r) * 600;
    for (int c = ln; c < 600; c += 64) op[c] = row[c] * inv;
  }
}

extern "C" void kernel_launch(void* const* d_in, const int* in_sizes, int n_in,
                              void* d_out, int out_size, void* d_ws, size_t ws_size,
                              hipStream_t stream) {
  const float* bH = (const float*)d_in[0];
  const int* text = (const int*)d_in[1];  // harness converts int64 -> int32
  const float* Wi2h = (const float*)d_in[2];
  const float* Wh2h = (const float*)d_in[3];
  const float* bh2h = (const float*)d_in[4];
  const float* Wsc = (const float*)d_in[5];
  const float* Wih = (const float*)d_in[6];
  const float* Whh = (const float*)d_in[7];
  const float* bih = (const float*)d_in[8];
  const float* bhh = (const float*)d_in[9];
  const float* Wg = (const float*)d_in[10];
  const float* bg = (const float*)d_in[11];
  float* out = (float*)d_out;

  char* ws = (char*)d_ws;
  size_t off = 0;
  __half* Hp16 = (__half*)(ws + off);  off += (size_t)Bsz * Ssz * Hsz * 2;   // 67.1 MB
  __half* bHT = (__half*)(ws + off);   off += (size_t)Bsz * Vsz * Ssz * 2;   // 78.6 MB
  __half* hid16 = (__half*)(ws + off); off += (size_t)Tsz * Bsz * Hsz * 2;   // 15.9 MB
  float* WiT = (float*)(ws + off);     off += (size_t)600 * 512 * 4;         // 1.2 MB
  float* h_pp = (float*)(ws + off);    off += (size_t)2 * Bsz * Hsz * 4;     // 0.5 MB
  float* cb = (float*)(ws + off);      off += (size_t)2 * Bsz * Hsz * 4;     // 0.5 MB
  float* pp = (float*)(ws + off);      off += (size_t)Bsz * Hsz * 4;         // 0.25 MB
  float* ev = (float*)(ws + off);      off += (size_t)Bsz * Ssz * 4;         // 0.25 MB
  float* ctx = (float*)(ws + off);     off += (size_t)Bsz * Vsz * 4;         // 0.3 MB

  hipMemsetAsync(h_pp, 0, (size_t)2 * Bsz * Hsz * 4, stream);
  hipMemsetAsync(cb, 0, (size_t)2 * Bsz * Hsz * 4, stream);

  k_wt<<<dim3(25, 16), 256, 0, stream>>>(Wi2h, WiT);
  k_hp<<<(Bsz * Ssz) / 16, 256, 0, stream>>>(bH, WiT, Hp16, bHT);

  for (int t = 0; t < Tsz; ++t) {
    const float* hprev = h_pp + (size_t)(t & 1) * Bsz * Hsz;
    float* hnextf = h_pp + (size_t)((t + 1) & 1) * Bsz * Hsz;
    const float* cin = cb + (size_t)(t & 1) * Bsz * Hsz;
    float* cout = cb + (size_t)((t + 1) & 1) * Bsz * Hsz;
    k_pp<<<dim3(Bsz, 4), 512, 0, stream>>>(hprev, Wh2h, bh2h, pp);
    k_e<<<Bsz * 8, 512, 0, stream>>>(Hp16, pp, Wsc, ev);
    k_ctx<<<dim3(Bsz, 10), 512, 0, stream>>>(bHT, ev, ctx);
    k_gates<<<512, 512, 0, stream>>>(ctx, hprev, Wih, Whh, bih, bhh, text, t,
                                     cin, cout, hnextf,
                                     hid16 + (size_t)t * Bsz * Hsz);
  }

  k_gen<<<(Bsz * Tsz) / 16, 256, 0, stream>>>(hid16, Wg, bg, out);
}